// Round 1
// baseline (928.822 us; speedup 1.0000x reference)
//
#include <hip/hip_runtime.h>
#include <math.h>

typedef unsigned long long u64;

#define W 768
#define H 768
#define NP (768*768)
#define NB 8
#define WPR 12              // u64 words per row (768/64)
#define NW (NB*H*WPR)       // total words per bit buffer = 73728
#define FLOOD_PASSES 24

// ---------- ws layout (bytes) ----------
// 0       : gaussW[101] f32
// 512     : gabTab: 4 gabors x 140 f32 (hcos[35], hsin[35], vcos[35], vsin[35])
// 4096    : sc (u32): [0..7] imgMinEnc [8..15] imgMaxEnc [16..23] predMinEnc
//           [24..31] predMaxEnc [32..63] fsum(f32) [64..127] changed
// 8192    : partial[18432] f32
// 81920   : maskBits u64[NW]
// 671744  : seedBits u64[NW]
// 1261568 : reachBits u64[NW]
// 1851392 : b0, b2, b1, b3 : 4 x 4718592 f32

__device__ __forceinline__ unsigned fenc(float f) {
    unsigned b = __float_as_uint(f);
    return b ^ ((unsigned)((int)b >> 31) | 0x80000000u);
}
__device__ __forceinline__ float fdec(unsigned u) {
    unsigned b = (u & 0x80000000u) ? (u ^ 0x80000000u) : ~u;
    return __uint_as_float(b);
}
__device__ __forceinline__ int refl101(int i, int n) {
    if (i < 0) i = -i;
    if (i >= n) i = 2*n - 2 - i;
    return i;
}
__device__ __forceinline__ int symref(int i, int n) {
    if (i < 0) i = -1 - i;
    if (i >= n) i = 2*n - 1 - i;
    return i;
}

// ---------------- init: weight tables + scalar init ----------------
__global__ void initK(float* gaussW, float* gabTab, unsigned* sc) {
    int t = threadIdx.x;
    if (t < 101) {
        double sig = 15.5, s = 0.0;
        for (int i = 0; i < 101; i++) { double x = i - 50; s += exp(-x*x/(2.0*sig*sig)); }
        double x = t - 50;
        gaussW[t] = (float)(exp(-x*x/(2.0*sig*sig)) / s);
    }
    const double thetas[4] = {45.0, 90.0, 135.0, 180.0};
    const int    rad[4]    = {12, 17, 12, 17};
    for (int idx = t; idx < 4*35; idx += 256) {
        int g = idx / 35, k = idx % 35;
        int r = rad[g];
        double th = thetas[g] * (M_PI / 180.0);
        double sg = ((1.0/M_PI) * sqrt(log(2.0)/2.0) * 3.0) / 0.1;
        double a = 2.0*M_PI*0.1*cos(th);
        double b = 2.0*M_PI*0.1*sin(th);
        double C = 1.0/(2.0*M_PI*sg*sg);
        float* T = gabTab + g*140;
        if (k < 2*r + 1) {
            double d = (double)(k - r);
            double G = exp(-0.5*d*d/(sg*sg));
            T[k]       = (float)(C*G*cos(a*d));
            T[35 + k]  = (float)(C*G*sin(a*d));
            T[70 + k]  = (float)(G*cos(b*d));
            T[105 + k] = (float)(G*sin(b*d));
        } else {
            T[k] = T[35+k] = T[70+k] = T[105+k] = 0.f;
        }
    }
    if (t < 8)  { sc[t] = 0xFFFFFFFFu; sc[8+t] = 0u; sc[16+t] = 0xFFFFFFFFu; sc[24+t] = 0u; }
    if (t >= 32 && t < 64) ((float*)sc)[t] = 0.f;   // fsum
    if (t >= 64 && t < 128) sc[t] = 0u;             // changed flags
}

// ---------------- per-image min/max of img and pred ----------------
__global__ void reduceK(const float* __restrict__ img, const float* __restrict__ pred,
                        unsigned* sc) {
    int b = blockIdx.y;
    int base = b*NP + blockIdx.x*9216 + threadIdx.x;
    float imn = INFINITY, imx = -INFINITY, pmn = INFINITY, pmx = -INFINITY;
    for (int k = 0; k < 36; k++) {
        float v = img[base + k*256];  imn = fminf(imn, v); imx = fmaxf(imx, v);
        float p = pred[base + k*256]; pmn = fminf(pmn, p); pmx = fmaxf(pmx, p);
    }
    for (int off = 32; off; off >>= 1) {
        imn = fminf(imn, __shfl_down(imn, off));
        imx = fmaxf(imx, __shfl_down(imx, off));
        pmn = fminf(pmn, __shfl_down(pmn, off));
        pmx = fmaxf(pmx, __shfl_down(pmx, off));
    }
    __shared__ float s[4][4];
    int lane = threadIdx.x & 63, wv = threadIdx.x >> 6;
    if (lane == 0) { s[0][wv] = imn; s[1][wv] = imx; s[2][wv] = pmn; s[3][wv] = pmx; }
    __syncthreads();
    if (threadIdx.x == 0) {
        float a0 = s[0][0], a1 = s[1][0], a2 = s[2][0], a3 = s[3][0];
        for (int w = 1; w < 4; w++) {
            a0 = fminf(a0, s[0][w]); a1 = fmaxf(a1, s[1][w]);
            a2 = fminf(a2, s[2][w]); a3 = fmaxf(a3, s[3][w]);
        }
        atomicMin(&sc[b],      fenc(a0));
        atomicMax(&sc[8 + b],  fenc(a1));
        atomicMin(&sc[16 + b], fenc(a2));
        atomicMax(&sc[24 + b], fenc(a3));
    }
}

// ---------------- Gaussian blur H (fused normalize) ----------------
__global__ void gaussHK(const float* __restrict__ img, float* __restrict__ out,
                        const float* __restrict__ gw, const unsigned* __restrict__ sc) {
    int b = blockIdx.z, y = blockIdx.y, x0 = blockIdx.x * 256;
    float mn = fdec(sc[b]), mx = fdec(sc[8 + b]);
    float den = mx - mn;
    __shared__ float sh[356];
    const float* row = img + (b*H + y)*W;
    for (int i = threadIdx.x; i < 356; i += 256) {
        int gx = refl101(x0 - 50 + i, W);
        sh[i] = (row[gx] - mn) / den;
    }
    __syncthreads();
    float acc = 0.f;
    for (int i = 0; i < 101; i++) acc += gw[i] * sh[threadIdx.x + i];
    out[(b*H + y)*W + x0 + threadIdx.x] = acc;
}

// ---------------- Gaussian blur V + enh = clip(norm - bg) ----------------
__global__ void gaussVK(const float* __restrict__ tmp, const float* __restrict__ img,
                        float* __restrict__ enh, const float* __restrict__ gw,
                        const unsigned* __restrict__ sc) {
    int b = blockIdx.z, y = blockIdx.y, x = blockIdx.x*256 + threadIdx.x;
    float acc = 0.f;
    for (int j = 0; j < 101; j++) {
        int gy = refl101(y - 50 + j, H);
        acc += gw[j] * tmp[(b*H + gy)*W + x];
    }
    float mn = fdec(sc[b]), mx = fdec(sc[8 + b]);
    float v = (img[(b*H + y)*W + x] - mn) / (mx - mn);
    float e = v - acc;
    e = fminf(fmaxf(e, 0.f), 1.f);
    enh[(b*H + y)*W + x] = e;
}

// ---------------- Gabor horizontal (cos & sin lines) ----------------
__global__ void gaborHK(const float* __restrict__ enh, float* __restrict__ hc,
                        float* __restrict__ hs, const float* __restrict__ T, int r) {
    int b = blockIdx.z, y = blockIdx.y, x0 = blockIdx.x * 256;
    __shared__ float sh[256 + 34];
    const float* row = enh + (b*H + y)*W;
    int n = 256 + 2*r;
    for (int i = threadIdx.x; i < n; i += 256) {
        int gx = symref(x0 - r + i, W);
        sh[i] = row[gx];
    }
    __syncthreads();
    float ac = 0.f, as = 0.f;
    for (int i = 0; i <= 2*r; i++) {
        float v = sh[threadIdx.x + i];
        ac += T[i] * v;
        as += T[35 + i] * v;
    }
    int o = (b*H + y)*W + x0 + threadIdx.x;
    hc[o] = ac; hs[o] = as;
}

// ---------------- Gabor vertical + per-block partial sums ----------------
__global__ void gaborVK(const float* __restrict__ hc, const float* __restrict__ hs,
                        float* __restrict__ f, const float* __restrict__ T, int r,
                        float* __restrict__ partial) {
    int b = blockIdx.z, y = blockIdx.y, x = blockIdx.x*256 + threadIdx.x;
    float acc = 0.f;
    for (int j = 0; j <= 2*r; j++) {
        int gy = symref(y - r + j, H);
        int o = (b*H + gy)*W + x;
        acc += T[70 + j]*hc[o];
        acc -= T[105 + j]*hs[o];
    }
    f[(b*H + y)*W + x] = acc;
    float s = acc;
    for (int off = 32; off; off >>= 1) s += __shfl_down(s, off);
    __shared__ float sm[4];
    if ((threadIdx.x & 63) == 0) sm[threadIdx.x >> 6] = s;
    __syncthreads();
    if (threadIdx.x == 0)
        partial[(b*H + y)*3 + blockIdx.x] = ((sm[0] + sm[1]) + sm[2]) + sm[3];
}

// ---------------- deterministic per-image sum of partials ----------------
__global__ void sumK(const float* __restrict__ partial, float* fsum, int g) {
    int b = blockIdx.x;
    float s = 0.f;
    for (int k = 0; k < 9; k++) s += partial[b*2304 + threadIdx.x + k*256];
    __shared__ float sm[256];
    sm[threadIdx.x] = s; __syncthreads();
    for (int off = 128; off; off >>= 1) {
        if (threadIdx.x < off) sm[threadIdx.x] += sm[threadIdx.x + off];
        __syncthreads();
    }
    if (threadIdx.x == 0) fsum[g*8 + b] = sm[0];
}

// ---------------- seeds: local max of f above mean ----------------
__global__ void seedK(const float* __restrict__ f, const float* __restrict__ fsum,
                      u64* __restrict__ seedB, int g) {
    int b = blockIdx.z, y = blockIdx.y, x = blockIdx.x*256 + threadIdx.x;
    float mean = fsum[g*8 + b] / 589824.f;
    const float* F = f + b*NP;
    float c = F[y*W + x];
    float mx = c;
    int y0 = y > 0 ? y-1 : 0, y1 = y < H-1 ? y+1 : H-1;
    int x0 = x > 0 ? x-1 : 0, x1 = x < W-1 ? x+1 : W-1;
    for (int yy = y0; yy <= y1; yy++)
        for (int xx = x0; xx <= x1; xx++)
            mx = fmaxf(mx, F[yy*W + xx]);
    bool cond = (c == mx) && (c > mean);
    u64 m = __ballot(cond);
    if ((threadIdx.x & 63) == 0) {
        int word = blockIdx.x*4 + (threadIdx.x >> 6);
        seedB[(b*H + y)*WPR + word] |= m;
    }
}

// ---------------- Sobel grad mask (bitpacked) ----------------
__global__ void sobelK(const float* __restrict__ enh, u64* __restrict__ maskB) {
    int b = blockIdx.z, y = blockIdx.y, x = blockIdx.x*256 + threadIdx.x;
    const float* E = enh + b*NP;
    int ym = y > 0 ? y-1 : 1, yp = y < H-1 ? y+1 : H-2;   // reflect101
    int xm = x > 0 ? x-1 : 1, xp = x < W-1 ? x+1 : W-2;
    float a00 = E[ym*W + xm], a01 = E[ym*W + x], a02 = E[ym*W + xp];
    float a10 = E[y*W + xm],                     a12 = E[y*W + xp];
    float a20 = E[yp*W + xm], a21 = E[yp*W + x], a22 = E[yp*W + xp];
    // ascending-tap FMA chains matching conv order; +-1/+-2 multiplies are exact
    float gx = __fmaf_rn(-1.f, a00, 0.f);
    gx = __fmaf_rn( 1.f, a02, gx);
    gx = __fmaf_rn(-2.f, a10, gx);
    gx = __fmaf_rn( 2.f, a12, gx);
    gx = __fmaf_rn(-1.f, a20, gx);
    gx = __fmaf_rn( 1.f, a22, gx);
    float gy = __fmaf_rn(-1.f, a00, 0.f);
    gy = __fmaf_rn(-2.f, a01, gy);
    gy = __fmaf_rn(-1.f, a02, gy);
    gy = __fmaf_rn( 1.f, a20, gy);
    gy = __fmaf_rn( 2.f, a21, gy);
    gy = __fmaf_rn( 1.f, a22, gy);
    float s = __fadd_rn(__fmul_rn(gx, gx), __fmul_rn(gy, gy));
    float grad = (float)sqrt((double)s);   // correctly-rounded f32 sqrt
    const float TH = (float)(0.0789 + 1.0*0.0774);
    bool m = grad >= TH;
    u64 bits = __ballot(m);
    if ((threadIdx.x & 63) == 0) {
        int word = blockIdx.x*4 + (threadIdx.x >> 6);
        maskB[(b*H + y)*WPR + word] = bits;
    }
}

// ---------------- flood init: reach = mask & seed ----------------
__global__ void floodInitK(const u64* __restrict__ maskB, const u64* __restrict__ seedB,
                           u64* __restrict__ reachB) {
    int i = blockIdx.x*256 + threadIdx.x;
    if (i < NW) reachB[i] = maskB[i] & seedB[i];
}

// ---------------- flood pass: 64x64 bit tile, in-tile convergence ----------------
__global__ __launch_bounds__(64) void floodPassK(const u64* __restrict__ Mb,
                                                 u64* __restrict__ Rb,
                                                 unsigned* chg, int t) {
    if (t > 0 && chg[t-1] == 0) return;
    int b = blockIdx.z, wx = blockIdx.x, ty = blockIdx.y, lane = threadIdx.x;
    int gy = ty*64 + lane;
    const u64* M = Mb + (size_t)b*H*WPR;
    u64* R = Rb + (size_t)b*H*WPR;
    u64 m = M[gy*WPR + wx];
    u64 r = R[gy*WPR + wx];
    u64 orig = r;

    __shared__ unsigned char lB[66], rB[66];
    __shared__ u64 tb[2];
    for (int i = lane; i < 66; i += 64) {
        int row = ty*64 - 1 + i;
        unsigned char lv = 0, rv = 0;
        if (row >= 0 && row < H) {
            if (wx > 0)       lv = (unsigned char)((R[row*WPR + wx - 1] >> 63) & 1ULL);
            if (wx < WPR - 1) rv = (unsigned char)( R[row*WPR + wx + 1]        & 1ULL);
        }
        lB[i] = lv; rB[i] = rv;
    }
    if (lane == 0) tb[0] = (ty > 0)  ? R[(ty*64 - 1)*WPR + wx]  : 0ULL;
    if (lane == 1) tb[1] = (ty < 11) ? R[(ty*64 + 64)*WPR + wx] : 0ULL;
    __syncthreads();
    u64 top = tb[0], bot = tb[1];
    u64 cL = (lB[lane] | lB[lane+1] | lB[lane+2]) ? 1ULL : 0ULL;
    u64 cR = (rB[lane] | rB[lane+1] | rB[lane+2]) ? (1ULL << 63) : 0ULL;

    while (true) {
        u64 up = __shfl_up(r, 1);   if (lane == 0)  up = top;
        u64 dn = __shfl_down(r, 1); if (lane == 63) dn = bot;
        u64 D = up | r | dn;
        u64 nr = (D | (D << 1) | (D >> 1) | cL | cR) & m;
        if (!__any(nr != r)) break;
        r = nr;
    }
    R[gy*WPR + wx] = r;
    if (__any(r != orig)) { if (lane == 0) chg[t] = 1u; }
}

// ---------------- final: out = (sigmoid?(pred)>0.5) | reach ----------------
__global__ void finalK(const float* __restrict__ pred, const u64* __restrict__ reachB,
                       const unsigned* __restrict__ sc, float* __restrict__ out) {
    int b = blockIdx.z, y = blockIdx.y, x = blockIdx.x*256 + threadIdx.x;
    float pmn = fdec(sc[16 + b]), pmx = fdec(sc[24 + b]);
    bool needSig = (pmx > 1.0f) || (pmn < 0.0f);
    float p = pred[(b*H + y)*W + x];
    float pv;
    if (needSig) {
        float e = (float)exp(-(double)p);   // correctly-rounded f32 exp
        pv = 1.f / (1.f + e);
    } else {
        pv = p;
    }
    bool on = pv > 0.5f;
    u64 w = reachB[(b*H + y)*WPR + (x >> 6)];
    on = on || ((w >> (x & 63)) & 1ULL);
    out[(b*H + y)*W + x] = on ? 1.f : 0.f;
}

extern "C" void kernel_launch(void* const* d_in, const int* in_sizes, int n_in,
                              void* d_out, int out_size, void* d_ws, size_t ws_size,
                              hipStream_t stream) {
    const float* pred = (const float*)d_in[0];
    const float* img  = (const float*)d_in[1];
    float* out = (float*)d_out;
    char* ws = (char*)d_ws;

    float*    gaussW  = (float*)(ws);
    float*    gabTab  = (float*)(ws + 512);
    unsigned* sc      = (unsigned*)(ws + 4096);
    float*    fsum    = ((float*)sc) + 32;
    unsigned* chg     = sc + 64;
    float*    partial = (float*)(ws + 8192);
    u64*      maskB   = (u64*)(ws + 81920);
    u64*      seedB   = (u64*)(ws + 671744);
    u64*      reachB  = (u64*)(ws + 1261568);
    float*    b0 = (float*)(ws + 1851392);
    float*    b2 = b0 + (size_t)NB*NP;
    float*    b1 = b2 + (size_t)NB*NP;
    float*    b3 = b1 + (size_t)NB*NP;

    hipMemsetAsync(seedB, 0, (size_t)NW*sizeof(u64), stream);
    initK<<<1, 256, 0, stream>>>(gaussW, gabTab, sc);
    reduceK<<<dim3(64, 8), 256, 0, stream>>>(img, pred, sc);

    dim3 g3(3, H, NB);
    gaussHK<<<g3, 256, 0, stream>>>(img, b0, gaussW, sc);
    gaussVK<<<g3, 256, 0, stream>>>(b0, img, b1, gaussW, sc);

    const int rad[4] = {12, 17, 12, 17};
    for (int g = 0; g < 4; g++) {
        const float* T = gabTab + g*140;
        gaborHK<<<g3, 256, 0, stream>>>(b1, b0, b2, T, rad[g]);
        gaborVK<<<g3, 256, 0, stream>>>(b0, b2, b3, T, rad[g], partial);
        sumK<<<8, 256, 0, stream>>>(partial, fsum, g);
        seedK<<<g3, 256, 0, stream>>>(b3, fsum, seedB, g);
    }

    sobelK<<<g3, 256, 0, stream>>>(b1, maskB);
    floodInitK<<<288, 256, 0, stream>>>(maskB, seedB, reachB);
    for (int t = 0; t < FLOOD_PASSES; t++)
        floodPassK<<<dim3(12, 12, 8), 64, 0, stream>>>(maskB, reachB, chg, t);
    finalK<<<g3, 256, 0, stream>>>(pred, reachB, sc, out);
}

// Round 2
// 535.670 us; speedup vs baseline: 1.7339x; 1.7339x over previous
//
#include <hip/hip_runtime.h>
#include <math.h>

typedef unsigned long long u64;

#define W 768
#define H 768
#define NP (768*768)
#define NB 8
#define WPR 12              // u64 words per row (768/64)
#define NW (NB*H*WPR)       // total words per bit buffer = 73728
#define FLOOD_PASSES 24
#define TH 32               // output rows per block in tiled vertical convs

#define PADI(q) ((q) + ((q) >> 5))   // LDS pad: +1 word per 32 (breaks stride-4 conflicts)

// ---------- ws layout (bytes) ----------
// 1024    : wtab (floats): [0..106] gpadH  [128..290] gpadV
//           [512 + g*512 + 0..40] phc_g  [+64..104] phs_g
//           [512 + g*512 + 128..224] pvc_g [+256..352] pvs_g
// 16384   : sc (u32): [0..7] imgMinEnc [8..15] imgMaxEnc [16..23] predMinEnc
//           [24..31] predMaxEnc [32..63] fsum(f32) [64..127] changed
// 20480   : partial[18432] f32
// 98304   : maskBits u64[NW]
// 688128  : seedBits u64[NW]
// 1277952 : reachBits u64[NW]
// 1867776 : b0, b2, b1, b3 : 4 x 4718592 f32

__device__ __forceinline__ unsigned fenc(float f) {
    unsigned b = __float_as_uint(f);
    return b ^ ((unsigned)((int)b >> 31) | 0x80000000u);
}
__device__ __forceinline__ float fdec(unsigned u) {
    unsigned b = (u & 0x80000000u) ? (u ^ 0x80000000u) : ~u;
    return __uint_as_float(b);
}
__device__ __forceinline__ int refl101(int i, int n) {
    if (i < 0) i = -i;
    if (i >= n) i = 2*n - 2 - i;
    return i;
}
__device__ __forceinline__ int symref(int i, int n) {
    if (i < 0) i = -1 - i;
    if (i >= n) i = 2*n - 1 - i;
    return i;
}

// ---------------- init: zero-padded weight tables + scalar init ----------------
__global__ void initK(float* wtab, unsigned* sc) {
    int t = threadIdx.x;
    double sig = 15.5, ssum = 0.0;
    for (int i = 0; i < 101; i++) { double xx = i - 50; ssum += exp(-xx*xx/(2.0*sig*sig)); }
    for (int i = t; i < 107; i += 256) {        // gpadH: tap j at [3+j]
        float v = 0.f; int j = i - 3;
        if (j >= 0 && j < 101) { double xx = j - 50; v = (float)(exp(-xx*xx/(2.0*sig*sig))/ssum); }
        wtab[i] = v;
    }
    for (int i = t; i < 163; i += 256) {        // gpadV: tap j at [31+j]
        float v = 0.f; int j = i - 31;
        if (j >= 0 && j < 101) { double xx = j - 50; v = (float)(exp(-xx*xx/(2.0*sig*sig))/ssum); }
        wtab[128 + i] = v;
    }
    const double thetas[4] = {45.0, 90.0, 135.0, 180.0};
    const int    rad[4]    = {12, 17, 12, 17};
    for (int g = 0; g < 4; g++) {
        int r = rad[g];
        double th = thetas[g] * (M_PI / 180.0);
        double sg = ((1.0/M_PI) * sqrt(log(2.0)/2.0) * 3.0) / 0.1;
        double a  = 2.0*M_PI*0.1*cos(th);
        double bb = 2.0*M_PI*0.1*sin(th);
        double C  = 1.0/(2.0*M_PI*sg*sg);
        float* base = wtab + 512 + g*512;
        for (int i = t; i < 41; i += 256) {     // phc/phs: tap j at [3+j]
            int j = i - 3; float vc = 0.f, vs = 0.f;
            if (j >= 0 && j <= 2*r) {
                double d = (double)(j - r), G = exp(-0.5*d*d/(sg*sg));
                vc = (float)(C*G*cos(a*d)); vs = (float)(C*G*sin(a*d));
            }
            base[i] = vc; base[64 + i] = vs;
        }
        for (int i = t; i < 97; i += 256) {     // pvc/pvs: tap j at [31+j]
            int j = i - 31; float vc = 0.f, vs = 0.f;
            if (j >= 0 && j <= 2*r) {
                double d = (double)(j - r), G = exp(-0.5*d*d/(sg*sg));
                vc = (float)(G*cos(bb*d)); vs = (float)(G*sin(bb*d));
            }
            base[128 + i] = vc; base[256 + i] = vs;
        }
    }
    if (t < 8)  { sc[t] = 0xFFFFFFFFu; sc[8+t] = 0u; sc[16+t] = 0xFFFFFFFFu; sc[24+t] = 0u; }
    if (t >= 32 && t < 64) ((float*)sc)[t] = 0.f;   // fsum
    if (t >= 64 && t < 128) sc[t] = 0u;             // changed flags
}

// ---------------- per-image min/max of img and pred ----------------
__global__ void reduceK(const float* __restrict__ img, const float* __restrict__ pred,
                        unsigned* sc) {
    int b = blockIdx.y;
    int base = b*NP + blockIdx.x*9216 + threadIdx.x;
    float imn = INFINITY, imx = -INFINITY, pmn = INFINITY, pmx = -INFINITY;
    for (int k = 0; k < 36; k++) {
        float v = img[base + k*256];  imn = fminf(imn, v); imx = fmaxf(imx, v);
        float p = pred[base + k*256]; pmn = fminf(pmn, p); pmx = fmaxf(pmx, p);
    }
    for (int off = 32; off; off >>= 1) {
        imn = fminf(imn, __shfl_down(imn, off));
        imx = fmaxf(imx, __shfl_down(imx, off));
        pmn = fminf(pmn, __shfl_down(pmn, off));
        pmx = fmaxf(pmx, __shfl_down(pmx, off));
    }
    __shared__ float s[4][4];
    int lane = threadIdx.x & 63, wv = threadIdx.x >> 6;
    if (lane == 0) { s[0][wv] = imn; s[1][wv] = imx; s[2][wv] = pmn; s[3][wv] = pmx; }
    __syncthreads();
    if (threadIdx.x == 0) {
        float a0 = s[0][0], a1 = s[1][0], a2 = s[2][0], a3 = s[3][0];
        for (int w = 1; w < 4; w++) {
            a0 = fminf(a0, s[0][w]); a1 = fmaxf(a1, s[1][w]);
            a2 = fminf(a2, s[2][w]); a3 = fmaxf(a3, s[3][w]);
        }
        atomicMin(&sc[b],      fenc(a0));
        atomicMax(&sc[8 + b],  fenc(a1));
        atomicMin(&sc[16 + b], fenc(a2));
        atomicMax(&sc[24 + b], fenc(a3));
    }
}

// ---------------- Gaussian blur H: 4 outputs/thread, padded LDS ----------------
__global__ __launch_bounds__(192) void gaussHK2(const float* __restrict__ img,
                                                float* __restrict__ out,
                                                const float* __restrict__ wt,
                                                const unsigned* __restrict__ sc) {
    int b = blockIdx.y, y = blockIdx.x, t = threadIdx.x;
    float mn = fdec(sc[b]), mx = fdec(sc[8 + b]);
    float den = mx - mn;
    __shared__ float sh[896];
    const float* row = img + ((size_t)b*H + y)*W;
    for (int q = t; q < 868; q += 192) {
        int gx = refl101(q - 50, W);
        sh[PADI(q)] = (row[gx] - mn) / den;
    }
    __syncthreads();
    float a0 = 0.f, a1 = 0.f, a2 = 0.f, a3 = 0.f;
    int qb = 4*t;
    #pragma unroll
    for (int p = 0; p < 104; p++) {
        float v = sh[PADI(qb + p)];
        a0 = __fmaf_rn(wt[p + 3], v, a0);
        a1 = __fmaf_rn(wt[p + 2], v, a1);
        a2 = __fmaf_rn(wt[p + 1], v, a2);
        a3 = __fmaf_rn(wt[p    ], v, a3);
    }
    float4 o; o.x = a0; o.y = a1; o.z = a2; o.w = a3;
    *(float4*)(out + ((size_t)b*H + y)*W + qb) = o;
}

// ---------------- Gaussian blur V (tiled) + enh = clip(norm - bg) ----------------
__global__ __launch_bounds__(256) void gaussVK2(const float* __restrict__ tmp,
                                                const float* __restrict__ img,
                                                float* __restrict__ enh,
                                                const float* __restrict__ wt,
                                                const unsigned* __restrict__ sc) {
    int b = blockIdx.z, y0 = blockIdx.y*TH, x = blockIdx.x*256 + threadIdx.x;
    float acc[TH];
    #pragma unroll
    for (int k = 0; k < TH; k++) acc[k] = 0.f;
    const float* T = tmp + (size_t)b*NP;
    for (int base = 0; base < TH - 1 + 101; ++base) {
        int gy = refl101(y0 + base - 50, H);
        float v = T[gy*W + x];
        #pragma unroll
        for (int k = 0; k < TH; k++)
            acc[k] = __fmaf_rn(wt[base - k + 31], v, acc[k]);
    }
    float mn = fdec(sc[b]), mx = fdec(sc[8 + b]);
    float den = mx - mn;
    #pragma unroll
    for (int k = 0; k < TH; k++) {
        size_t o = ((size_t)b*H + y0 + k)*W + x;
        float vv = (img[o] - mn) / den;
        float e = vv - acc[k];
        e = fminf(fmaxf(e, 0.f), 1.f);
        enh[o] = e;
    }
}

// ---------------- Gabor H: 4 outputs/thread (cos & sin) ----------------
template<int R>
__global__ __launch_bounds__(192) void gaborHK2(const float* __restrict__ enh,
                                                float* __restrict__ hc,
                                                float* __restrict__ hs,
                                                const float* __restrict__ tc,
                                                const float* __restrict__ ts) {
    int b = blockIdx.y, y = blockIdx.x, t = threadIdx.x;
    __shared__ float sh[834];
    const float* row = enh + ((size_t)b*H + y)*W;
    for (int q = t; q < 768 + 2*R; q += 192) {
        int gx = symref(q - R, W);
        sh[PADI(q)] = row[gx];
    }
    __syncthreads();
    float c0 = 0.f, c1 = 0.f, c2 = 0.f, c3 = 0.f;
    float s0 = 0.f, s1 = 0.f, s2 = 0.f, s3 = 0.f;
    int qb = 4*t;
    #pragma unroll
    for (int p = 0; p < 2*R + 4; p++) {
        float v = sh[PADI(qb + p)];
        c0 = __fmaf_rn(tc[p + 3], v, c0);  s0 = __fmaf_rn(ts[p + 3], v, s0);
        c1 = __fmaf_rn(tc[p + 2], v, c1);  s1 = __fmaf_rn(ts[p + 2], v, s1);
        c2 = __fmaf_rn(tc[p + 1], v, c2);  s2 = __fmaf_rn(ts[p + 1], v, s2);
        c3 = __fmaf_rn(tc[p    ], v, c3);  s3 = __fmaf_rn(ts[p    ], v, s3);
    }
    size_t o = ((size_t)b*H + y)*W + qb;
    float4 vc; vc.x = c0; vc.y = c1; vc.z = c2; vc.w = c3;
    float4 vs; vs.x = s0; vs.y = s1; vs.z = s2; vs.w = s3;
    *(float4*)(hc + o) = vc;
    *(float4*)(hs + o) = vs;
}

// ---------------- Gabor V (tiled) + per-row partial sums ----------------
template<int R>
__global__ __launch_bounds__(256) void gaborVK2(const float* __restrict__ hc,
                                                const float* __restrict__ hs,
                                                float* __restrict__ f,
                                                const float* __restrict__ tc,
                                                const float* __restrict__ ts,
                                                float* __restrict__ partial) {
    int b = blockIdx.z, y0 = blockIdx.y*TH, x = blockIdx.x*256 + threadIdx.x;
    float acc[TH];
    #pragma unroll
    for (int k = 0; k < TH; k++) acc[k] = 0.f;
    for (int base = 0; base < TH + 2*R; ++base) {
        int gy = symref(y0 + base - R, H);
        size_t o = ((size_t)b*H + gy)*W + x;
        float hcv = hc[o], hsv = hs[o];
        #pragma unroll
        for (int k = 0; k < TH; k++) {
            float wc = tc[base - k + 31];
            float ws_ = ts[base - k + 31];
            acc[k] = __fmaf_rn(wc, hcv, acc[k]);
            acc[k] = __fmaf_rn(-ws_, hsv, acc[k]);
        }
    }
    __shared__ float smAll[TH][4];
    int wv = threadIdx.x >> 6;
    #pragma unroll
    for (int k = 0; k < TH; k++) {
        f[((size_t)b*H + y0 + k)*W + x] = acc[k];
        float s = acc[k];
        for (int off = 32; off; off >>= 1) s += __shfl_down(s, off);
        if ((threadIdx.x & 63) == 0) smAll[k][wv] = s;
    }
    __syncthreads();
    if (threadIdx.x < TH) {
        int k = threadIdx.x;
        float p4 = ((smAll[k][0] + smAll[k][1]) + smAll[k][2]) + smAll[k][3];
        partial[((size_t)b*H + y0 + k)*3 + blockIdx.x] = p4;
    }
}

// ---------------- deterministic per-image sum of partials ----------------
__global__ void sumK(const float* __restrict__ partial, float* fsum, int g) {
    int b = blockIdx.x;
    float s = 0.f;
    for (int k = 0; k < 9; k++) s += partial[b*2304 + threadIdx.x + k*256];
    __shared__ float sm[256];
    sm[threadIdx.x] = s; __syncthreads();
    for (int off = 128; off; off >>= 1) {
        if (threadIdx.x < off) sm[threadIdx.x] += sm[threadIdx.x + off];
        __syncthreads();
    }
    if (threadIdx.x == 0) fsum[g*8 + b] = sm[0];
}

// ---------------- seeds: local max of f above mean ----------------
__global__ void seedK(const float* __restrict__ f, const float* __restrict__ fsum,
                      u64* __restrict__ seedB, int g) {
    int b = blockIdx.z, y = blockIdx.y, x = blockIdx.x*256 + threadIdx.x;
    float mean = fsum[g*8 + b] / 589824.f;
    const float* F = f + (size_t)b*NP;
    float c = F[y*W + x];
    float mx = c;
    int y0 = y > 0 ? y-1 : 0, y1 = y < H-1 ? y+1 : H-1;
    int x0 = x > 0 ? x-1 : 0, x1 = x < W-1 ? x+1 : W-1;
    for (int yy = y0; yy <= y1; yy++)
        for (int xx = x0; xx <= x1; xx++)
            mx = fmaxf(mx, F[yy*W + xx]);
    bool cond = (c == mx) && (c > mean);
    u64 m = __ballot(cond);
    if ((threadIdx.x & 63) == 0) {
        int word = blockIdx.x*4 + (threadIdx.x >> 6);
        seedB[((size_t)b*H + y)*WPR + word] |= m;
    }
}

// ---------------- Sobel grad mask (bitpacked) ----------------
__global__ void sobelK(const float* __restrict__ enh, u64* __restrict__ maskB) {
    int b = blockIdx.z, y = blockIdx.y, x = blockIdx.x*256 + threadIdx.x;
    const float* E = enh + (size_t)b*NP;
    int ym = y > 0 ? y-1 : 1, yp = y < H-1 ? y+1 : H-2;   // reflect101
    int xm = x > 0 ? x-1 : 1, xp = x < W-1 ? x+1 : W-2;
    float a00 = E[ym*W + xm], a01 = E[ym*W + x], a02 = E[ym*W + xp];
    float a10 = E[y*W + xm],                     a12 = E[y*W + xp];
    float a20 = E[yp*W + xm], a21 = E[yp*W + x], a22 = E[yp*W + xp];
    float gx = __fmaf_rn(-1.f, a00, 0.f);
    gx = __fmaf_rn( 1.f, a02, gx);
    gx = __fmaf_rn(-2.f, a10, gx);
    gx = __fmaf_rn( 2.f, a12, gx);
    gx = __fmaf_rn(-1.f, a20, gx);
    gx = __fmaf_rn( 1.f, a22, gx);
    float gy = __fmaf_rn(-1.f, a00, 0.f);
    gy = __fmaf_rn(-2.f, a01, gy);
    gy = __fmaf_rn(-1.f, a02, gy);
    gy = __fmaf_rn( 1.f, a20, gy);
    gy = __fmaf_rn( 2.f, a21, gy);
    gy = __fmaf_rn( 1.f, a22, gy);
    float s = __fadd_rn(__fmul_rn(gx, gx), __fmul_rn(gy, gy));
    float grad = (float)sqrt((double)s);
    const float THR = (float)(0.0789 + 1.0*0.0774);
    bool m = grad >= THR;
    u64 bits = __ballot(m);
    if ((threadIdx.x & 63) == 0) {
        int word = blockIdx.x*4 + (threadIdx.x >> 6);
        maskB[((size_t)b*H + y)*WPR + word] = bits;
    }
}

// ---------------- flood init: reach = mask & seed ----------------
__global__ void floodInitK(const u64* __restrict__ maskB, const u64* __restrict__ seedB,
                           u64* __restrict__ reachB) {
    int i = blockIdx.x*256 + threadIdx.x;
    if (i < NW) reachB[i] = maskB[i] & seedB[i];
}

// ---------------- flood pass: 64x64 bit tile, in-tile convergence ----------------
__global__ __launch_bounds__(64) void floodPassK(const u64* __restrict__ Mb,
                                                 u64* __restrict__ Rb,
                                                 unsigned* chg, int t) {
    if (t > 0 && chg[t-1] == 0) return;
    int b = blockIdx.z, wx = blockIdx.x, ty = blockIdx.y, lane = threadIdx.x;
    int gy = ty*64 + lane;
    const u64* M = Mb + (size_t)b*H*WPR;
    u64* R = Rb + (size_t)b*H*WPR;
    u64 m = M[gy*WPR + wx];
    u64 r = R[gy*WPR + wx];
    u64 orig = r;

    __shared__ unsigned char lB[66], rB[66];
    __shared__ u64 tb[2];
    for (int i = lane; i < 66; i += 64) {
        int row = ty*64 - 1 + i;
        unsigned char lv = 0, rv = 0;
        if (row >= 0 && row < H) {
            if (wx > 0)       lv = (unsigned char)((R[row*WPR + wx - 1] >> 63) & 1ULL);
            if (wx < WPR - 1) rv = (unsigned char)( R[row*WPR + wx + 1]        & 1ULL);
        }
        lB[i] = lv; rB[i] = rv;
    }
    if (lane == 0) tb[0] = (ty > 0)  ? R[(ty*64 - 1)*WPR + wx]  : 0ULL;
    if (lane == 1) tb[1] = (ty < 11) ? R[(ty*64 + 64)*WPR + wx] : 0ULL;
    __syncthreads();
    u64 top = tb[0], bot = tb[1];
    u64 cL = (lB[lane] | lB[lane+1] | lB[lane+2]) ? 1ULL : 0ULL;
    u64 cR = (rB[lane] | rB[lane+1] | rB[lane+2]) ? (1ULL << 63) : 0ULL;

    while (true) {
        u64 up = __shfl_up(r, 1);   if (lane == 0)  up = top;
        u64 dn = __shfl_down(r, 1); if (lane == 63) dn = bot;
        u64 D = up | r | dn;
        u64 nr = (D | (D << 1) | (D >> 1) | cL | cR) & m;
        if (!__any(nr != r)) break;
        r = nr;
    }
    R[gy*WPR + wx] = r;
    if (__any(r != orig)) { if (lane == 0) chg[t] = 1u; }
}

// ---------------- final: out = (sigmoid?(pred)>0.5) | reach ----------------
__global__ void finalK(const float* __restrict__ pred, const u64* __restrict__ reachB,
                       const unsigned* __restrict__ sc, float* __restrict__ out) {
    int b = blockIdx.z, y = blockIdx.y, x = blockIdx.x*256 + threadIdx.x;
    float pmn = fdec(sc[16 + b]), pmx = fdec(sc[24 + b]);
    bool needSig = (pmx > 1.0f) || (pmn < 0.0f);
    float p = pred[((size_t)b*H + y)*W + x];
    float pv;
    if (needSig) {
        float e = (float)exp(-(double)p);
        pv = 1.f / (1.f + e);
    } else {
        pv = p;
    }
    bool on = pv > 0.5f;
    u64 w = reachB[((size_t)b*H + y)*WPR + (x >> 6)];
    on = on || ((w >> (x & 63)) & 1ULL);
    out[((size_t)b*H + y)*W + x] = on ? 1.f : 0.f;
}

extern "C" void kernel_launch(void* const* d_in, const int* in_sizes, int n_in,
                              void* d_out, int out_size, void* d_ws, size_t ws_size,
                              hipStream_t stream) {
    const float* pred = (const float*)d_in[0];
    const float* img  = (const float*)d_in[1];
    float* out = (float*)d_out;
    char* ws = (char*)d_ws;

    float*    wtab    = (float*)(ws + 1024);
    unsigned* sc      = (unsigned*)(ws + 16384);
    float*    fsum    = ((float*)sc) + 32;
    unsigned* chg     = sc + 64;
    float*    partial = (float*)(ws + 20480);
    u64*      maskB   = (u64*)(ws + 98304);
    u64*      seedB   = (u64*)(ws + 688128);
    u64*      reachB  = (u64*)(ws + 1277952);
    float*    b0 = (float*)(ws + 1867776);
    float*    b2 = b0 + (size_t)NB*NP;
    float*    b1 = b2 + (size_t)NB*NP;
    float*    b3 = b1 + (size_t)NB*NP;

    const float* gpadH = wtab;
    const float* gpadV = wtab + 128;

    hipMemsetAsync(seedB, 0, (size_t)NW*sizeof(u64), stream);
    initK<<<1, 256, 0, stream>>>(wtab, sc);
    reduceK<<<dim3(64, 8), 256, 0, stream>>>(img, pred, sc);

    dim3 gRow(768, 8);           // one image row per block (H passes)
    dim3 gTile(3, H/TH, 8);      // 256-col strips x 32-row tiles (V passes)
    dim3 g3(3, H, 8);            // per-pixel kernels

    gaussHK2<<<gRow, 192, 0, stream>>>(img, b0, gpadH, sc);
    gaussVK2<<<gTile, 256, 0, stream>>>(b0, img, b1, gpadV, sc);

    for (int g = 0; g < 4; g++) {
        const float* ang = wtab + 512 + g*512;
        const float* phc = ang,      * phs = ang + 64;
        const float* pvc = ang + 128,* pvs = ang + 256;
        if (g == 0 || g == 2) {
            gaborHK2<12><<<gRow, 192, 0, stream>>>(b1, b0, b2, phc, phs);
            gaborVK2<12><<<gTile, 256, 0, stream>>>(b0, b2, b3, pvc, pvs, partial);
        } else {
            gaborHK2<17><<<gRow, 192, 0, stream>>>(b1, b0, b2, phc, phs);
            gaborVK2<17><<<gTile, 256, 0, stream>>>(b0, b2, b3, pvc, pvs, partial);
        }
        sumK<<<8, 256, 0, stream>>>(partial, fsum, g);
        seedK<<<g3, 256, 0, stream>>>(b3, fsum, seedB, g);
    }

    sobelK<<<g3, 256, 0, stream>>>(b1, maskB);
    floodInitK<<<288, 256, 0, stream>>>(maskB, seedB, reachB);
    for (int t = 0; t < FLOOD_PASSES; t++)
        floodPassK<<<dim3(12, 12, 8), 64, 0, stream>>>(maskB, reachB, chg, t);
    finalK<<<g3, 256, 0, stream>>>(pred, reachB, sc, out);
}

// Round 3
// 437.059 us; speedup vs baseline: 2.1252x; 1.2256x over previous
//
#include <hip/hip_runtime.h>
#include <math.h>

typedef unsigned long long u64;

#define W 768
#define H 768
#define NP (768*768)
#define NB 8
#define WPR 12              // u64 words per row (768/64)
#define NW (NB*H*WPR)       // total words per bit buffer = 73728
#define FLOOD_PASSES 16
#define TH 16               // output rows per block in tiled vertical convs

#define PADI(q) ((q) + ((q) >> 5))   // LDS pad: +1 word per 32

// ---------- ws layout (bytes) ----------
// 1024    : wtab (floats): [0..106] gpadH  [128..290] gpadV
//           [512 + g*512 + 0..40] phc_g  [+64..104] phs_g
//           [512 + g*512 + 128..224] pvc_g [+256..352] pvs_g
// 16384   : sc (u32): [0..7] imgMinEnc [8..15] imgMaxEnc [16..23] predMinEnc
//           [24..31] predMaxEnc [32..63] fsum(f32) [64..127] changed
// 20480   : partial12[8*768*12] f32 (294912 B)
// 327680  : maskBits u64[NW]
// 917504  : seedBits u64[NW]
// 1507328 : reachBits u64[NW]
// 2097152 : b0, b2, b1, b3 : 4 x 4718592 f32

__device__ __forceinline__ unsigned fenc(float f) {
    unsigned b = __float_as_uint(f);
    return b ^ ((unsigned)((int)b >> 31) | 0x80000000u);
}
__device__ __forceinline__ float fdec(unsigned u) {
    unsigned b = (u & 0x80000000u) ? (u ^ 0x80000000u) : ~u;
    return __uint_as_float(b);
}
__device__ __forceinline__ int refl101(int i, int n) {
    if (i < 0) i = -i;
    if (i >= n) i = 2*n - 2 - i;
    return i;
}
__device__ __forceinline__ int symref(int i, int n) {
    if (i < 0) i = -1 - i;
    if (i >= n) i = 2*n - 1 - i;
    return i;
}

// ---------------- init: zero-padded weight tables + scalar init ----------------
__global__ void initK(float* wtab, unsigned* sc) {
    int t = threadIdx.x;
    double sig = 15.5, ssum = 0.0;
    for (int i = 0; i < 101; i++) { double xx = i - 50; ssum += exp(-xx*xx/(2.0*sig*sig)); }
    for (int i = t; i < 107; i += 256) {        // gpadH: tap j at [3+j]
        float v = 0.f; int j = i - 3;
        if (j >= 0 && j < 101) { double xx = j - 50; v = (float)(exp(-xx*xx/(2.0*sig*sig))/ssum); }
        wtab[i] = v;
    }
    for (int i = t; i < 163; i += 256) {        // gpadV: tap j at [31+j]
        float v = 0.f; int j = i - 31;
        if (j >= 0 && j < 101) { double xx = j - 50; v = (float)(exp(-xx*xx/(2.0*sig*sig))/ssum); }
        wtab[128 + i] = v;
    }
    const double thetas[4] = {45.0, 90.0, 135.0, 180.0};
    const int    rad[4]    = {12, 17, 12, 17};
    for (int g = 0; g < 4; g++) {
        int r = rad[g];
        double th = thetas[g] * (M_PI / 180.0);
        double sg = ((1.0/M_PI) * sqrt(log(2.0)/2.0) * 3.0) / 0.1;
        double a  = 2.0*M_PI*0.1*cos(th);
        double bb = 2.0*M_PI*0.1*sin(th);
        double C  = 1.0/(2.0*M_PI*sg*sg);
        float* base = wtab + 512 + g*512;
        for (int i = t; i < 41; i += 256) {     // phc/phs: tap j at [3+j]
            int j = i - 3; float vc = 0.f, vs = 0.f;
            if (j >= 0 && j <= 2*r) {
                double d = (double)(j - r), G = exp(-0.5*d*d/(sg*sg));
                vc = (float)(C*G*cos(a*d)); vs = (float)(C*G*sin(a*d));
            }
            base[i] = vc; base[64 + i] = vs;
        }
        for (int i = t; i < 97; i += 256) {     // pvc/pvs: tap j at [31+j]
            int j = i - 31; float vc = 0.f, vs = 0.f;
            if (j >= 0 && j <= 2*r) {
                double d = (double)(j - r), G = exp(-0.5*d*d/(sg*sg));
                vc = (float)(G*cos(bb*d)); vs = (float)(G*sin(bb*d));
            }
            base[128 + i] = vc; base[256 + i] = vs;
        }
    }
    if (t < 8)  { sc[t] = 0xFFFFFFFFu; sc[8+t] = 0u; sc[16+t] = 0xFFFFFFFFu; sc[24+t] = 0u; }
    if (t >= 32 && t < 64) ((float*)sc)[t] = 0.f;       // fsum
    if (t >= 64 && t < 128) sc[t] = (t == 64) ? 1u : 0u; // changed flags; chg[0]=1
}

// ---------------- per-image min/max of img and pred ----------------
__global__ void reduceK(const float* __restrict__ img, const float* __restrict__ pred,
                        unsigned* sc) {
    int b = blockIdx.y;
    int base = b*NP + blockIdx.x*9216 + threadIdx.x;
    float imn = INFINITY, imx = -INFINITY, pmn = INFINITY, pmx = -INFINITY;
    for (int k = 0; k < 36; k++) {
        float v = img[base + k*256];  imn = fminf(imn, v); imx = fmaxf(imx, v);
        float p = pred[base + k*256]; pmn = fminf(pmn, p); pmx = fmaxf(pmx, p);
    }
    for (int off = 32; off; off >>= 1) {
        imn = fminf(imn, __shfl_down(imn, off));
        imx = fmaxf(imx, __shfl_down(imx, off));
        pmn = fminf(pmn, __shfl_down(pmn, off));
        pmx = fmaxf(pmx, __shfl_down(pmx, off));
    }
    __shared__ float s[4][4];
    int lane = threadIdx.x & 63, wv = threadIdx.x >> 6;
    if (lane == 0) { s[0][wv] = imn; s[1][wv] = imx; s[2][wv] = pmn; s[3][wv] = pmx; }
    __syncthreads();
    if (threadIdx.x == 0) {
        float a0 = s[0][0], a1 = s[1][0], a2 = s[2][0], a3 = s[3][0];
        for (int w = 1; w < 4; w++) {
            a0 = fminf(a0, s[0][w]); a1 = fmaxf(a1, s[1][w]);
            a2 = fminf(a2, s[2][w]); a3 = fmaxf(a3, s[3][w]);
        }
        atomicMin(&sc[b],      fenc(a0));
        atomicMax(&sc[8 + b],  fenc(a1));
        atomicMin(&sc[16 + b], fenc(a2));
        atomicMax(&sc[24 + b], fenc(a3));
    }
}

// ---------------- Gaussian blur H: 4 outputs/thread, padded LDS ----------------
__global__ __launch_bounds__(192) void gaussHK2(const float* __restrict__ img,
                                                float* __restrict__ out,
                                                const float* __restrict__ wt,
                                                const unsigned* __restrict__ sc) {
    int b = blockIdx.y, y = blockIdx.x, t = threadIdx.x;
    float mn = fdec(sc[b]), mx = fdec(sc[8 + b]);
    float den = mx - mn;
    __shared__ float sh[896];
    const float* row = img + ((size_t)b*H + y)*W;
    for (int q = t; q < 868; q += 192) {
        int gx = refl101(q - 50, W);
        sh[PADI(q)] = (row[gx] - mn) / den;
    }
    __syncthreads();
    float a0 = 0.f, a1 = 0.f, a2 = 0.f, a3 = 0.f;
    int qb = 4*t;
    #pragma unroll
    for (int p = 0; p < 104; p++) {
        float v = sh[PADI(qb + p)];
        a0 = __fmaf_rn(wt[p + 3], v, a0);
        a1 = __fmaf_rn(wt[p + 2], v, a1);
        a2 = __fmaf_rn(wt[p + 1], v, a2);
        a3 = __fmaf_rn(wt[p    ], v, a3);
    }
    float4 o; o.x = a0; o.y = a1; o.z = a2; o.w = a3;
    *(float4*)(out + ((size_t)b*H + y)*W + qb) = o;
}

// ---------------- Gaussian blur V (TH=16 tile) + enh = clip(norm - bg) ----------------
__global__ __launch_bounds__(128) void gaussVK3(const float* __restrict__ tmp,
                                                const float* __restrict__ img,
                                                float* __restrict__ enh,
                                                const float* __restrict__ wt,
                                                const unsigned* __restrict__ sc) {
    int b = blockIdx.z, y0 = blockIdx.y*TH, x = blockIdx.x*128 + threadIdx.x;
    float acc[TH];
    #pragma unroll
    for (int k = 0; k < TH; k++) acc[k] = 0.f;
    const float* T = tmp + (size_t)b*NP;
    for (int base = 0; base < TH - 1 + 101; ++base) {
        int gy = refl101(y0 + base - 50, H);
        float v = T[gy*W + x];
        #pragma unroll
        for (int k = 0; k < TH; k++)
            acc[k] = __fmaf_rn(wt[base - k + 31], v, acc[k]);
    }
    float mn = fdec(sc[b]), mx = fdec(sc[8 + b]);
    float den = mx - mn;
    #pragma unroll
    for (int k = 0; k < TH; k++) {
        size_t o = ((size_t)b*H + y0 + k)*W + x;
        float vv = (img[o] - mn) / den;
        float e = vv - acc[k];
        e = fminf(fmaxf(e, 0.f), 1.f);
        enh[o] = e;
    }
}

// ---------------- Gabor H: 4 outputs/thread (cos & sin) ----------------
template<int R>
__global__ __launch_bounds__(192) void gaborHK2(const float* __restrict__ enh,
                                                float* __restrict__ hc,
                                                float* __restrict__ hs,
                                                const float* __restrict__ tc,
                                                const float* __restrict__ ts) {
    int b = blockIdx.y, y = blockIdx.x, t = threadIdx.x;
    __shared__ float sh[834];
    const float* row = enh + ((size_t)b*H + y)*W;
    for (int q = t; q < 768 + 2*R; q += 192) {
        int gx = symref(q - R, W);
        sh[PADI(q)] = row[gx];
    }
    __syncthreads();
    float c0 = 0.f, c1 = 0.f, c2 = 0.f, c3 = 0.f;
    float s0 = 0.f, s1 = 0.f, s2 = 0.f, s3 = 0.f;
    int qb = 4*t;
    #pragma unroll
    for (int p = 0; p < 2*R + 4; p++) {
        float v = sh[PADI(qb + p)];
        c0 = __fmaf_rn(tc[p + 3], v, c0);  s0 = __fmaf_rn(ts[p + 3], v, s0);
        c1 = __fmaf_rn(tc[p + 2], v, c1);  s1 = __fmaf_rn(ts[p + 2], v, s1);
        c2 = __fmaf_rn(tc[p + 1], v, c2);  s2 = __fmaf_rn(ts[p + 1], v, s2);
        c3 = __fmaf_rn(tc[p    ], v, c3);  s3 = __fmaf_rn(ts[p    ], v, s3);
    }
    size_t o = ((size_t)b*H + y)*W + qb;
    float4 vc; vc.x = c0; vc.y = c1; vc.z = c2; vc.w = c3;
    float4 vs; vs.x = s0; vs.y = s1; vs.z = s2; vs.w = s3;
    *(float4*)(hc + o) = vc;
    *(float4*)(hs + o) = vs;
}

// ---------------- Gabor V (TH=16 tile) + per-64col wave partial sums ----------------
template<int R>
__global__ __launch_bounds__(128) void gaborVK3(const float* __restrict__ hc,
                                                const float* __restrict__ hs,
                                                float* __restrict__ f,
                                                const float* __restrict__ tc,
                                                const float* __restrict__ ts,
                                                float* __restrict__ p12) {
    int b = blockIdx.z, y0 = blockIdx.y*TH, x = blockIdx.x*128 + threadIdx.x;
    float acc[TH];
    #pragma unroll
    for (int k = 0; k < TH; k++) acc[k] = 0.f;
    for (int base = 0; base < TH + 2*R; ++base) {
        int gy = symref(y0 + base - R, H);
        size_t o = ((size_t)b*H + gy)*W + x;
        float hcv = hc[o], hsv = hs[o];
        #pragma unroll
        for (int k = 0; k < TH; k++) {
            acc[k] = __fmaf_rn(tc[base - k + 31], hcv, acc[k]);
            acc[k] = __fmaf_rn(-ts[base - k + 31], hsv, acc[k]);
        }
    }
    int g64 = blockIdx.x*2 + (threadIdx.x >> 6);   // global 64-col group 0..11
    #pragma unroll
    for (int k = 0; k < TH; k++) {
        f[((size_t)b*H + y0 + k)*W + x] = acc[k];
        float s = acc[k];
        for (int off = 32; off; off >>= 1) s += __shfl_down(s, off);
        if ((threadIdx.x & 63) == 0)
            p12[((size_t)b*H + y0 + k)*12 + g64] = s;
    }
}

// ---------------- deterministic per-image sum (recombine exact old tree) ----------------
__global__ void sumK2(const float* __restrict__ p12, float* fsum, int g) {
    int b = blockIdx.x, t = threadIdx.x;
    float s = 0.f;
    for (int k = 0; k < 9; k++) {
        int idx = t + k*256;                 // 0..2303 == row*3 + strip
        int row = idx / 3, strip = idx - row*3;
        const float* P = p12 + ((size_t)b*H + row)*12 + strip*4;
        float p4 = ((P[0] + P[1]) + P[2]) + P[3];
        s += p4;
    }
    __shared__ float sm[256];
    sm[t] = s; __syncthreads();
    for (int off = 128; off; off >>= 1) {
        if (t < off) sm[t] += sm[t + off];
        __syncthreads();
    }
    if (t == 0) fsum[g*8 + b] = sm[0];
}

// ---------------- seeds: local max of f above mean (row-LDS) ----------------
__global__ void seedK2(const float* __restrict__ f, const float* __restrict__ fsum,
                       u64* __restrict__ seedB, int g) {
    int b = blockIdx.z, y = blockIdx.y, x0 = blockIdx.x*256, t = threadIdx.x;
    __shared__ float sh[3][258];
    const float* F = f + (size_t)b*NP;
    int ym = y > 0 ? y-1 : 0, yp = y < H-1 ? y+1 : H-1;
    const float* r0 = F + ym*W;
    const float* r1 = F + y*W;
    const float* r2 = F + yp*W;
    for (int q = t; q < 258; q += 256) {
        int gx = x0 - 1 + q;
        gx = gx < 0 ? 0 : (gx > W-1 ? W-1 : gx);
        sh[0][q] = r0[gx]; sh[1][q] = r1[gx]; sh[2][q] = r2[gx];
    }
    __syncthreads();
    float c = sh[1][t + 1];
    float mx = c;
    #pragma unroll
    for (int dy = 0; dy < 3; dy++)
        #pragma unroll
        for (int dx = 0; dx < 3; dx++)
            mx = fmaxf(mx, sh[dy][t + dx]);
    float mean = fsum[g*8 + b] / 589824.f;
    bool cond = (c == mx) && (c > mean);
    u64 m = __ballot(cond);
    if ((t & 63) == 0) {
        int word = blockIdx.x*4 + (t >> 6);
        seedB[((size_t)b*H + y)*WPR + word] |= m;
    }
}

// ---------------- Sobel grad mask (bitpacked) ----------------
__global__ void sobelK(const float* __restrict__ enh, u64* __restrict__ maskB) {
    int b = blockIdx.z, y = blockIdx.y, x = blockIdx.x*256 + threadIdx.x;
    const float* E = enh + (size_t)b*NP;
    int ym = y > 0 ? y-1 : 1, yp = y < H-1 ? y+1 : H-2;   // reflect101
    int xm = x > 0 ? x-1 : 1, xp = x < W-1 ? x+1 : W-2;
    float a00 = E[ym*W + xm], a01 = E[ym*W + x], a02 = E[ym*W + xp];
    float a10 = E[y*W + xm],                     a12 = E[y*W + xp];
    float a20 = E[yp*W + xm], a21 = E[yp*W + x], a22 = E[yp*W + xp];
    float gx = __fmaf_rn(-1.f, a00, 0.f);
    gx = __fmaf_rn( 1.f, a02, gx);
    gx = __fmaf_rn(-2.f, a10, gx);
    gx = __fmaf_rn( 2.f, a12, gx);
    gx = __fmaf_rn(-1.f, a20, gx);
    gx = __fmaf_rn( 1.f, a22, gx);
    float gy = __fmaf_rn(-1.f, a00, 0.f);
    gy = __fmaf_rn(-2.f, a01, gy);
    gy = __fmaf_rn(-1.f, a02, gy);
    gy = __fmaf_rn( 1.f, a20, gy);
    gy = __fmaf_rn( 2.f, a21, gy);
    gy = __fmaf_rn( 1.f, a22, gy);
    float s = __fadd_rn(__fmul_rn(gx, gx), __fmul_rn(gy, gy));
    float grad = (float)sqrt((double)s);
    const float THR = (float)(0.0789 + 1.0*0.0774);
    bool m = grad >= THR;
    u64 bits = __ballot(m);
    if ((threadIdx.x & 63) == 0) {
        int word = blockIdx.x*4 + (threadIdx.x >> 6);
        maskB[((size_t)b*H + y)*WPR + word] = bits;
    }
}

// ---------------- flood pass: 64-col x 768-row stripe in registers ----------------
__global__ __launch_bounds__(64) void floodColK(const u64* __restrict__ Mb,
                                                const u64* __restrict__ seedB,
                                                u64* __restrict__ Rb,
                                                unsigned* __restrict__ chg, int t) {
    if (t > 0 && chg[t-1] == 0) return;
    int b = blockIdx.y, wx = blockIdx.x, lane = threadIdx.x;
    const u64* M = Mb + (size_t)b*H*WPR;
    u64* R = Rb + (size_t)b*H*WPR;
    u64 m[12], r[12];
    #pragma unroll
    for (int j = 0; j < 12; j++) {
        int row = j*64 + lane;
        m[j] = M[row*WPR + wx];
        if (t == 0) r[j] = m[j] & seedB[((size_t)b*H + row)*WPR + wx];
        else        r[j] = R[row*WPR + wx];
    }
    // horizontal neighbor edge-bit columns (snapshot; zero on pass 0)
    unsigned cLmask = 0, cRmask = 0;   // bit j = this lane's row in tile j touches left/right-in
    {
        u64 CL[12], CR[12];
        #pragma unroll
        for (int j = 0; j < 12; j++) {
            int row = j*64 + lane;
            unsigned lv = 0, rv = 0;
            if (t > 0) {
                if (wx > 0)       lv = (unsigned)((R[row*WPR + wx - 1] >> 63) & 1ULL);
                if (wx < WPR - 1) rv = (unsigned)( R[row*WPR + wx + 1]        & 1ULL);
            }
            CL[j] = __ballot(lv != 0); CR[j] = __ballot(rv != 0);
        }
        #pragma unroll
        for (int j = 0; j < 12; j++) {
            u64 p = (j > 0)  ? CL[j-1] : 0ULL, n = (j < 11) ? CL[j+1] : 0ULL;
            u64 d = CL[j] | (CL[j] << 1) | (CL[j] >> 1) | (p >> 63) | (n << 63);
            cLmask |= (unsigned)((d >> lane) & 1ULL) << j;
            u64 p2 = (j > 0)  ? CR[j-1] : 0ULL, n2 = (j < 11) ? CR[j+1] : 0ULL;
            u64 d2 = CR[j] | (CR[j] << 1) | (CR[j] >> 1) | (p2 >> 63) | (n2 << 63);
            cRmask |= (unsigned)((d2 >> lane) & 1ULL) << j;
        }
    }
    bool grew = false;
    while (true) {
        bool any = false;
        #pragma unroll
        for (int j = 0; j < 12; j++) {
            u64 top = (j > 0)  ? __shfl(r[j-1], 63) : 0ULL;
            u64 bot = (j < 11) ? __shfl(r[j+1], 0)  : 0ULL;
            u64 up = __shfl_up(r[j], 1);   if (lane == 0)  up = top;
            u64 dn = __shfl_down(r[j], 1); if (lane == 63) dn = bot;
            u64 D = up | r[j] | dn;
            u64 nr = (D | (D << 1) | (D >> 1)
                      | (u64)((cLmask >> j) & 1u)
                      | ((u64)((cRmask >> j) & 1u) << 63)) & m[j];
            if (nr != r[j]) any = true;
            r[j] = nr;
        }
        if (!__any(any)) break;
        grew = true;
    }
    #pragma unroll
    for (int j = 0; j < 12; j++) R[(j*64 + lane)*WPR + wx] = r[j];
    if (__any(grew)) { if (lane == 0) atomicOr(&chg[t], 1u); }
}

// ---------------- final: out = (sigmoid?(pred)>0.5) | reach ----------------
__global__ void finalK(const float* __restrict__ pred, const u64* __restrict__ reachB,
                       const unsigned* __restrict__ sc, float* __restrict__ out) {
    int b = blockIdx.z, y = blockIdx.y, x = blockIdx.x*256 + threadIdx.x;
    float pmn = fdec(sc[16 + b]), pmx = fdec(sc[24 + b]);
    bool needSig = (pmx > 1.0f) || (pmn < 0.0f);
    float p = pred[((size_t)b*H + y)*W + x];
    float pv;
    if (needSig) {
        float e = (float)exp(-(double)p);
        pv = 1.f / (1.f + e);
    } else {
        pv = p;
    }
    bool on = pv > 0.5f;
    u64 w = reachB[((size_t)b*H + y)*WPR + (x >> 6)];
    on = on || ((w >> (x & 63)) & 1ULL);
    out[((size_t)b*H + y)*W + x] = on ? 1.f : 0.f;
}

extern "C" void kernel_launch(void* const* d_in, const int* in_sizes, int n_in,
                              void* d_out, int out_size, void* d_ws, size_t ws_size,
                              hipStream_t stream) {
    const float* pred = (const float*)d_in[0];
    const float* img  = (const float*)d_in[1];
    float* out = (float*)d_out;
    char* ws = (char*)d_ws;

    float*    wtab    = (float*)(ws + 1024);
    unsigned* sc      = (unsigned*)(ws + 16384);
    float*    fsum    = ((float*)sc) + 32;
    unsigned* chg     = sc + 64;
    float*    p12     = (float*)(ws + 20480);
    u64*      maskB   = (u64*)(ws + 327680);
    u64*      seedB   = (u64*)(ws + 917504);
    u64*      reachB  = (u64*)(ws + 1507328);
    float*    b0 = (float*)(ws + 2097152);
    float*    b2 = b0 + (size_t)NB*NP;
    float*    b1 = b2 + (size_t)NB*NP;
    float*    b3 = b1 + (size_t)NB*NP;

    const float* gpadH = wtab;
    const float* gpadV = wtab + 128;

    hipMemsetAsync(seedB, 0, (size_t)NW*sizeof(u64), stream);
    initK<<<1, 256, 0, stream>>>(wtab, sc);
    reduceK<<<dim3(64, 8), 256, 0, stream>>>(img, pred, sc);

    dim3 gRow(768, 8);            // one image row per block (H passes)
    dim3 gV(6, H/TH, 8);          // 128-col strips x 16-row tiles (V passes)
    dim3 g3(3, H, 8);             // per-pixel kernels

    gaussHK2<<<gRow, 192, 0, stream>>>(img, b0, gpadH, sc);
    gaussVK3<<<gV, 128, 0, stream>>>(b0, img, b1, gpadV, sc);

    for (int g = 0; g < 4; g++) {
        const float* ang = wtab + 512 + g*512;
        const float* phc = ang,       * phs = ang + 64;
        const float* pvc = ang + 128, * pvs = ang + 256;
        if (g == 0 || g == 2) {
            gaborHK2<12><<<gRow, 192, 0, stream>>>(b1, b0, b2, phc, phs);
            gaborVK3<12><<<gV, 128, 0, stream>>>(b0, b2, b3, pvc, pvs, p12);
        } else {
            gaborHK2<17><<<gRow, 192, 0, stream>>>(b1, b0, b2, phc, phs);
            gaborVK3<17><<<gV, 128, 0, stream>>>(b0, b2, b3, pvc, pvs, p12);
        }
        sumK2<<<8, 256, 0, stream>>>(p12, fsum, g);
        seedK2<<<g3, 256, 0, stream>>>(b3, fsum, seedB, g);
    }

    sobelK<<<g3, 256, 0, stream>>>(b1, maskB);
    for (int t = 0; t < FLOOD_PASSES; t++)
        floodColK<<<dim3(12, 8), 64, 0, stream>>>(maskB, seedB, reachB, chg, t);
    finalK<<<g3, 256, 0, stream>>>(pred, reachB, sc, out);
}

// Round 4
// 335.495 us; speedup vs baseline: 2.7685x; 1.3027x over previous
//
#include <hip/hip_runtime.h>
#include <math.h>

typedef unsigned long long u64;

#define W 768
#define H 768
#define NP (768*768)
#define NB 8
#define WPR 12              // u64 words per row (768/64)
#define NW (NB*H*WPR)       // total words per bit buffer = 73728
#define FLOOD_PASSES 16
#define TH 16               // output rows per block in tiled vertical convs

#define PADI(q) ((q) + ((q) >> 5))   // LDS pad: +1 word per 32

// ---------- ws layout (bytes) ----------
// 1024    : wtab (floats, 1536 entries):
//           [0..106] gpadH, [128..290] gpadV
//           [384+p*64]  6 uniform-17 horizontal tables (41 real entries):
//                p: 0=h0c 1=h0s 2=h1c 3=h2c 4=h2s 5=h3c
//           [768+q*128] 6 vertical tables: q: 0=v0c(R12) 1=v0s(R12) 2=v1c(R17)
//                3=v2c(R12) 4=v2s(R12) 5=v3c(R17)
// 16384   : sc (u32): [0..7] imgMinEnc [8..15] imgMaxEnc [16..23] predMinEnc
//           [24..31] predMaxEnc [32..63] fsum(f32) [64..127] changed
// 20480   : p12[8*768*12] f32 (294912 B)
// 4 MiB   : 12 planes of 18,874,368 B each:
//           0:b0(tmp) 1:b1(enh) 2:h0c 3:h0s 4:h1c 5:h2c 6:h2s 7:h3c 8:f0 9:f1 10:f2 11:f3
//           total end = 4,194,304 + 226,492,416 = 230,686,720  (ws = 256 MiB)

__device__ __forceinline__ unsigned fenc(float f) {
    unsigned b = __float_as_uint(f);
    return b ^ ((unsigned)((int)b >> 31) | 0x80000000u);
}
__device__ __forceinline__ float fdec(unsigned u) {
    unsigned b = (u & 0x80000000u) ? (u ^ 0x80000000u) : ~u;
    return __uint_as_float(b);
}
__device__ __forceinline__ int refl101(int i, int n) {
    if (i < 0) i = -i;
    if (i >= n) i = 2*n - 2 - i;
    return i;
}
__device__ __forceinline__ int symref(int i, int n) {
    if (i < 0) i = -1 - i;
    if (i >= n) i = 2*n - 1 - i;
    return i;
}

// ---------------- init: weight tables + scalar init ----------------
__global__ void initK(float* wtab, unsigned* sc) {
    int t = threadIdx.x;
    double sig = 15.5, ssum = 0.0;
    for (int i = 0; i < 101; i++) { double xx = i - 50; ssum += exp(-xx*xx/(2.0*sig*sig)); }
    for (int i = t; i < 107; i += 256) {        // gpadH: tap j at [3+j]
        float v = 0.f; int j = i - 3;
        if (j >= 0 && j < 101) { double xx = j - 50; v = (float)(exp(-xx*xx/(2.0*sig*sig))/ssum); }
        wtab[i] = v;
    }
    for (int i = t; i < 163; i += 256) {        // gpadV: tap j at [31+j]
        float v = 0.f; int j = i - 31;
        if (j >= 0 && j < 101) { double xx = j - 50; v = (float)(exp(-xx*xx/(2.0*sig*sig))/ssum); }
        wtab[128 + i] = v;
    }
    const double thetas[4] = {45.0, 90.0, 135.0, 180.0};
    const int    rad[4]    = {12, 17, 12, 17};
    const double sg = ((1.0/M_PI) * sqrt(log(2.0)/2.0) * 3.0) / 0.1;
    const double C  = 1.0/(2.0*M_PI*sg*sg);
    // horizontal uniform-17 tables: plane -> (gabor, isSin)
    const int hG[6]   = {0, 0, 1, 2, 2, 3};
    const int hSin[6] = {0, 1, 0, 0, 1, 0};
    for (int idx = t; idx < 6*64; idx += 256) {
        int p = idx / 64, i = idx % 64;
        int g = hG[p], r = rad[g];
        double th = thetas[g] * (M_PI / 180.0);
        double a  = 2.0*M_PI*0.1*cos(th);
        float v = 0.f;
        int d = i - 20;                         // entry i <-> tap j17=i-3 <-> d=j17-17
        if (i < 41 && d >= -r && d <= r) {
            double dd = (double)d, G = exp(-0.5*dd*dd/(sg*sg));
            v = hSin[p] ? (float)(C*G*sin(a*dd)) : (float)(C*G*cos(a*dd));
        }
        wtab[384 + p*64 + i] = v;
    }
    // vertical tables (per-R layout, tap j at [31+j], d=j-R)
    const int vG[6]   = {0, 0, 1, 2, 2, 3};
    const int vSin[6] = {0, 1, 0, 0, 1, 0};
    for (int idx = t; idx < 6*128; idx += 256) {
        int q = idx / 128, i = idx % 128;
        int g = vG[q], r = rad[g];
        double th = thetas[g] * (M_PI / 180.0);
        double bb = 2.0*M_PI*0.1*sin(th);
        float v = 0.f;
        int j = i - 31;
        if (j >= 0 && j <= 2*r) {
            double dd = (double)(j - r), G = exp(-0.5*dd*dd/(sg*sg));
            v = vSin[q] ? (float)(G*sin(bb*dd)) : (float)(G*cos(bb*dd));
        }
        wtab[768 + q*128 + i] = v;
    }
    if (t < 8)  { sc[t] = 0xFFFFFFFFu; sc[8+t] = 0u; sc[16+t] = 0xFFFFFFFFu; sc[24+t] = 0u; }
    if (t >= 32 && t < 64) ((float*)sc)[t] = 0.f;        // fsum
    if (t >= 64 && t < 128) sc[t] = (t == 64) ? 1u : 0u; // changed flags; chg[0]=1
}

// ---------------- per-image min/max of img and pred ----------------
__global__ void reduceK(const float* __restrict__ img, const float* __restrict__ pred,
                        unsigned* sc) {
    int b = blockIdx.y;
    int base = b*NP + blockIdx.x*9216 + threadIdx.x;
    float imn = INFINITY, imx = -INFINITY, pmn = INFINITY, pmx = -INFINITY;
    for (int k = 0; k < 36; k++) {
        float v = img[base + k*256];  imn = fminf(imn, v); imx = fmaxf(imx, v);
        float p = pred[base + k*256]; pmn = fminf(pmn, p); pmx = fmaxf(pmx, p);
    }
    for (int off = 32; off; off >>= 1) {
        imn = fminf(imn, __shfl_down(imn, off));
        imx = fmaxf(imx, __shfl_down(imx, off));
        pmn = fminf(pmn, __shfl_down(pmn, off));
        pmx = fmaxf(pmx, __shfl_down(pmx, off));
    }
    __shared__ float s[4][4];
    int lane = threadIdx.x & 63, wv = threadIdx.x >> 6;
    if (lane == 0) { s[0][wv] = imn; s[1][wv] = imx; s[2][wv] = pmn; s[3][wv] = pmx; }
    __syncthreads();
    if (threadIdx.x == 0) {
        float a0 = s[0][0], a1 = s[1][0], a2 = s[2][0], a3 = s[3][0];
        for (int w = 1; w < 4; w++) {
            a0 = fminf(a0, s[0][w]); a1 = fmaxf(a1, s[1][w]);
            a2 = fminf(a2, s[2][w]); a3 = fmaxf(a3, s[3][w]);
        }
        atomicMin(&sc[b],      fenc(a0));
        atomicMax(&sc[8 + b],  fenc(a1));
        atomicMin(&sc[16 + b], fenc(a2));
        atomicMax(&sc[24 + b], fenc(a3));
    }
}

// ---------------- Gaussian blur H: 4 outputs/thread, padded LDS ----------------
__global__ __launch_bounds__(192) void gaussHK2(const float* __restrict__ img,
                                                float* __restrict__ out,
                                                const float* __restrict__ wt,
                                                const unsigned* __restrict__ sc) {
    int b = blockIdx.y, y = blockIdx.x, t = threadIdx.x;
    float mn = fdec(sc[b]), mx = fdec(sc[8 + b]);
    float den = mx - mn;
    __shared__ float sh[896];
    const float* row = img + ((size_t)b*H + y)*W;
    for (int q = t; q < 868; q += 192) {
        int gx = refl101(q - 50, W);
        sh[PADI(q)] = (row[gx] - mn) / den;
    }
    __syncthreads();
    float a0 = 0.f, a1 = 0.f, a2 = 0.f, a3 = 0.f;
    int qb = 4*t;
    #pragma unroll
    for (int p = 0; p < 104; p++) {
        float v = sh[PADI(qb + p)];
        a0 = __fmaf_rn(wt[p + 3], v, a0);
        a1 = __fmaf_rn(wt[p + 2], v, a1);
        a2 = __fmaf_rn(wt[p + 1], v, a2);
        a3 = __fmaf_rn(wt[p    ], v, a3);
    }
    float4 o; o.x = a0; o.y = a1; o.z = a2; o.w = a3;
    *(float4*)(out + ((size_t)b*H + y)*W + qb) = o;
}

// ---------------- Gaussian blur V: unroll x4, XCD-resident image ----------------
__global__ __launch_bounds__(128) void gaussVK4(const float* __restrict__ tmp,
                                                const float* __restrict__ img,
                                                float* __restrict__ enh,
                                                const float* __restrict__ wt,
                                                const unsigned* __restrict__ sc) {
    int bid = blockIdx.x;
    int b = bid & 7; int r_ = bid >> 3; int tile = r_ % 48; int strip = r_ / 48;
    int y0 = tile*TH, x = strip*128 + threadIdx.x;
    float acc[TH];
    #pragma unroll
    for (int k = 0; k < TH; k++) acc[k] = 0.f;
    const float* T = tmp + (size_t)b*NP;
    for (int base = 0; base < 116; base += 4) {
        int g0 = refl101(y0+base-50, H), g1 = refl101(y0+base-49, H),
            g2 = refl101(y0+base-48, H), g3 = refl101(y0+base-47, H);
        float v0 = T[g0*W+x], v1 = T[g1*W+x], v2 = T[g2*W+x], v3 = T[g3*W+x];
        #pragma unroll
        for (int k = 0; k < TH; k++) {
            float a = acc[k];
            a = __fmaf_rn(wt[base   -k+31], v0, a);
            a = __fmaf_rn(wt[base+1 -k+31], v1, a);
            a = __fmaf_rn(wt[base+2 -k+31], v2, a);
            a = __fmaf_rn(wt[base+3 -k+31], v3, a);
            acc[k] = a;
        }
    }
    float mn = fdec(sc[b]), mx = fdec(sc[8 + b]);
    float den = mx - mn;
    #pragma unroll
    for (int k = 0; k < TH; k++) {
        size_t o = ((size_t)b*H + y0 + k)*W + x;
        float vv = (img[o] - mn) / den;
        float e = vv - acc[k];
        e = fminf(fmaxf(e, 0.f), 1.f);
        enh[o] = e;
    }
}

// ---------------- fused Gabor H: 6 planes in one pass ----------------
__global__ __launch_bounds__(192) void gaborHF(const float* __restrict__ enh,
        float* __restrict__ h0c, float* __restrict__ h0s, float* __restrict__ h1c,
        float* __restrict__ h2c, float* __restrict__ h2s, float* __restrict__ h3c,
        const float* __restrict__ wt) {
    int b = blockIdx.y, y = blockIdx.x, t = threadIdx.x;
    __shared__ float sh[832];
    const float* row = enh + ((size_t)b*H + y)*W;
    for (int q = t; q < 802; q += 192) {
        int gx = symref(q - 17, W);
        sh[PADI(q)] = row[gx];
    }
    __syncthreads();
    const float* T0c = wt + 384; const float* T0s = wt + 448; const float* T1c = wt + 512;
    const float* T2c = wt + 576; const float* T2s = wt + 640; const float* T3c = wt + 704;
    float a0c[4] = {0,0,0,0}, a0s[4] = {0,0,0,0}, a1c[4] = {0,0,0,0};
    float a2c[4] = {0,0,0,0}, a2s[4] = {0,0,0,0}, a3c[4] = {0,0,0,0};
    int qb = 4*t;
    #pragma unroll
    for (int p = 0; p < 38; p++) {
        float v = sh[PADI(qb + p)];
        #pragma unroll
        for (int sub = 0; sub < 4; sub++) {
            int idx = p + 3 - sub;
            a0c[sub] = __fmaf_rn(T0c[idx], v, a0c[sub]);
            a0s[sub] = __fmaf_rn(T0s[idx], v, a0s[sub]);
            a1c[sub] = __fmaf_rn(T1c[idx], v, a1c[sub]);
            a2c[sub] = __fmaf_rn(T2c[idx], v, a2c[sub]);
            a2s[sub] = __fmaf_rn(T2s[idx], v, a2s[sub]);
            a3c[sub] = __fmaf_rn(T3c[idx], v, a3c[sub]);
        }
    }
    size_t o = ((size_t)b*H + y)*W + qb;
    *(float4*)(h0c + o) = make_float4(a0c[0], a0c[1], a0c[2], a0c[3]);
    *(float4*)(h0s + o) = make_float4(a0s[0], a0s[1], a0s[2], a0s[3]);
    *(float4*)(h1c + o) = make_float4(a1c[0], a1c[1], a1c[2], a1c[3]);
    *(float4*)(h2c + o) = make_float4(a2c[0], a2c[1], a2c[2], a2c[3]);
    *(float4*)(h2s + o) = make_float4(a2s[0], a2s[1], a2s[2], a2s[3]);
    *(float4*)(h3c + o) = make_float4(a3c[0], a3c[1], a3c[2], a3c[3]);
}

// ---------------- Gabor V, 2-plane (R=12), unroll x4 ----------------
__global__ __launch_bounds__(128) void gaborV2pK(const float* __restrict__ hc,
        const float* __restrict__ hs, float* __restrict__ f,
        const float* __restrict__ tc, const float* __restrict__ ts,
        float* __restrict__ p12) {
    int bid = blockIdx.x;
    int b = bid & 7; int r_ = bid >> 3; int tile = r_ % 48; int strip = r_ / 48;
    int y0 = tile*TH, x = strip*128 + threadIdx.x;
    float acc[TH];
    #pragma unroll
    for (int k = 0; k < TH; k++) acc[k] = 0.f;
    const size_t pb = (size_t)b*NP;
    for (int base = 0; base < 40; base += 4) {
        int g0 = symref(y0+base-12, H), g1 = symref(y0+base-11, H),
            g2 = symref(y0+base-10, H), g3 = symref(y0+base-9, H);
        size_t o0 = pb + (size_t)g0*W + x, o1 = pb + (size_t)g1*W + x;
        size_t o2 = pb + (size_t)g2*W + x, o3 = pb + (size_t)g3*W + x;
        float c0 = hc[o0], c1 = hc[o1], c2 = hc[o2], c3 = hc[o3];
        float s0 = hs[o0], s1 = hs[o1], s2 = hs[o2], s3 = hs[o3];
        #pragma unroll
        for (int k = 0; k < TH; k++) {
            float a = acc[k];
            a = __fmaf_rn( tc[base   -k+31], c0, a); a = __fmaf_rn(-ts[base   -k+31], s0, a);
            a = __fmaf_rn( tc[base+1 -k+31], c1, a); a = __fmaf_rn(-ts[base+1 -k+31], s1, a);
            a = __fmaf_rn( tc[base+2 -k+31], c2, a); a = __fmaf_rn(-ts[base+2 -k+31], s2, a);
            a = __fmaf_rn( tc[base+3 -k+31], c3, a); a = __fmaf_rn(-ts[base+3 -k+31], s3, a);
            acc[k] = a;
        }
    }
    int g64 = strip*2 + (threadIdx.x >> 6);
    #pragma unroll
    for (int k = 0; k < TH; k++) {
        f[((size_t)b*H + y0 + k)*W + x] = acc[k];
        float s = acc[k];
        for (int off = 32; off; off >>= 1) s += __shfl_down(s, off);
        if ((threadIdx.x & 63) == 0)
            p12[((size_t)b*H + y0 + k)*12 + g64] = s;
    }
}

// ---------------- Gabor V, 1-plane (R=17), unroll x4 ----------------
__global__ __launch_bounds__(128) void gaborV1pK(const float* __restrict__ hc,
        float* __restrict__ f, const float* __restrict__ tc,
        float* __restrict__ p12) {
    int bid = blockIdx.x;
    int b = bid & 7; int r_ = bid >> 3; int tile = r_ % 48; int strip = r_ / 48;
    int y0 = tile*TH, x = strip*128 + threadIdx.x;
    float acc[TH];
    #pragma unroll
    for (int k = 0; k < TH; k++) acc[k] = 0.f;
    const size_t pb = (size_t)b*NP;
    for (int base = 0; base < 48; base += 4) {
        int g0 = symref(y0+base-17, H), g1 = symref(y0+base-16, H),
            g2 = symref(y0+base-15, H), g3 = symref(y0+base-14, H);
        float c0 = hc[pb + (size_t)g0*W + x], c1 = hc[pb + (size_t)g1*W + x];
        float c2 = hc[pb + (size_t)g2*W + x], c3 = hc[pb + (size_t)g3*W + x];
        #pragma unroll
        for (int k = 0; k < TH; k++) {
            float a = acc[k];
            a = __fmaf_rn(tc[base   -k+31], c0, a);
            a = __fmaf_rn(tc[base+1 -k+31], c1, a);
            a = __fmaf_rn(tc[base+2 -k+31], c2, a);
            a = __fmaf_rn(tc[base+3 -k+31], c3, a);
            acc[k] = a;
        }
    }
    // remainder: base = 48, 49
    {
        int g0 = symref(y0+48-17, H), g1 = symref(y0+49-17, H);
        float c0 = hc[pb + (size_t)g0*W + x], c1 = hc[pb + (size_t)g1*W + x];
        #pragma unroll
        for (int k = 0; k < TH; k++) {
            float a = acc[k];
            a = __fmaf_rn(tc[48 -k+31], c0, a);
            a = __fmaf_rn(tc[49 -k+31], c1, a);
            acc[k] = a;
        }
    }
    int g64 = strip*2 + (threadIdx.x >> 6);
    #pragma unroll
    for (int k = 0; k < TH; k++) {
        f[((size_t)b*H + y0 + k)*W + x] = acc[k];
        float s = acc[k];
        for (int off = 32; off; off >>= 1) s += __shfl_down(s, off);
        if ((threadIdx.x & 63) == 0)
            p12[((size_t)b*H + y0 + k)*12 + g64] = s;
    }
}

// ---------------- deterministic per-image sum (exact old tree) ----------------
__global__ void sumK2(const float* __restrict__ p12, float* fsum, int g) {
    int b = blockIdx.x, t = threadIdx.x;
    float s = 0.f;
    for (int k = 0; k < 9; k++) {
        int idx = t + k*256;                 // 0..2303 == row*3 + strip
        int row = idx / 3, strip = idx - row*3;
        const float* P = p12 + ((size_t)b*H + row)*12 + strip*4;
        float p4 = ((P[0] + P[1]) + P[2]) + P[3];
        s += p4;
    }
    __shared__ float sm[256];
    sm[t] = s; __syncthreads();
    for (int off = 128; off; off >>= 1) {
        if (t < off) sm[t] += sm[t + off];
        __syncthreads();
    }
    if (t == 0) fsum[g*8 + b] = sm[0];
}

// ---------------- fused seeds: 4 angles in one pass, direct store ----------------
__global__ __launch_bounds__(256) void seedK3(const float* __restrict__ f0,
        const float* __restrict__ f1, const float* __restrict__ f2,
        const float* __restrict__ f3, const float* __restrict__ fsum,
        u64* __restrict__ seedB) {
    int b = blockIdx.z, y = blockIdx.y, x0 = blockIdx.x*256, t = threadIdx.x;
    __shared__ float sh[4][3][258];
    int ym = y > 0 ? y-1 : 0, yp = y < H-1 ? y+1 : H-1;
    {
        const float* Fb = f0 + (size_t)b*NP;
        const float* r0 = Fb + ym*W; const float* r1 = Fb + y*W; const float* r2 = Fb + yp*W;
        for (int q = t; q < 258; q += 256) {
            int gx = x0 - 1 + q; gx = gx < 0 ? 0 : (gx > W-1 ? W-1 : gx);
            sh[0][0][q] = r0[gx]; sh[0][1][q] = r1[gx]; sh[0][2][q] = r2[gx];
        }
    }
    {
        const float* Fb = f1 + (size_t)b*NP;
        const float* r0 = Fb + ym*W; const float* r1 = Fb + y*W; const float* r2 = Fb + yp*W;
        for (int q = t; q < 258; q += 256) {
            int gx = x0 - 1 + q; gx = gx < 0 ? 0 : (gx > W-1 ? W-1 : gx);
            sh[1][0][q] = r0[gx]; sh[1][1][q] = r1[gx]; sh[1][2][q] = r2[gx];
        }
    }
    {
        const float* Fb = f2 + (size_t)b*NP;
        const float* r0 = Fb + ym*W; const float* r1 = Fb + y*W; const float* r2 = Fb + yp*W;
        for (int q = t; q < 258; q += 256) {
            int gx = x0 - 1 + q; gx = gx < 0 ? 0 : (gx > W-1 ? W-1 : gx);
            sh[2][0][q] = r0[gx]; sh[2][1][q] = r1[gx]; sh[2][2][q] = r2[gx];
        }
    }
    {
        const float* Fb = f3 + (size_t)b*NP;
        const float* r0 = Fb + ym*W; const float* r1 = Fb + y*W; const float* r2 = Fb + yp*W;
        for (int q = t; q < 258; q += 256) {
            int gx = x0 - 1 + q; gx = gx < 0 ? 0 : (gx > W-1 ? W-1 : gx);
            sh[3][0][q] = r0[gx]; sh[3][1][q] = r1[gx]; sh[3][2][q] = r2[gx];
        }
    }
    __syncthreads();
    bool any = false;
    #pragma unroll
    for (int a = 0; a < 4; a++) {
        float c = sh[a][1][t + 1];
        float mx = c;
        #pragma unroll
        for (int dy = 0; dy < 3; dy++)
            #pragma unroll
            for (int dx = 0; dx < 3; dx++)
                mx = fmaxf(mx, sh[a][dy][t + dx]);
        float mean = fsum[a*8 + b] / 589824.f;
        any = any || ((c == mx) && (c > mean));
    }
    u64 m = __ballot(any);
    if ((t & 63) == 0)
        seedB[((size_t)b*H + y)*WPR + blockIdx.x*4 + (t >> 6)] = m;
}

// ---------------- Sobel grad mask (bitpacked) ----------------
__global__ void sobelK(const float* __restrict__ enh, u64* __restrict__ maskB) {
    int b = blockIdx.z, y = blockIdx.y, x = blockIdx.x*256 + threadIdx.x;
    const float* E = enh + (size_t)b*NP;
    int ym = y > 0 ? y-1 : 1, yp = y < H-1 ? y+1 : H-2;   // reflect101
    int xm = x > 0 ? x-1 : 1, xp = x < W-1 ? x+1 : W-2;
    float a00 = E[ym*W + xm], a01 = E[ym*W + x], a02 = E[ym*W + xp];
    float a10 = E[y*W + xm],                     a12 = E[y*W + xp];
    float a20 = E[yp*W + xm], a21 = E[yp*W + x], a22 = E[yp*W + xp];
    float gx = __fmaf_rn(-1.f, a00, 0.f);
    gx = __fmaf_rn( 1.f, a02, gx);
    gx = __fmaf_rn(-2.f, a10, gx);
    gx = __fmaf_rn( 2.f, a12, gx);
    gx = __fmaf_rn(-1.f, a20, gx);
    gx = __fmaf_rn( 1.f, a22, gx);
    float gy = __fmaf_rn(-1.f, a00, 0.f);
    gy = __fmaf_rn(-2.f, a01, gy);
    gy = __fmaf_rn(-1.f, a02, gy);
    gy = __fmaf_rn( 1.f, a20, gy);
    gy = __fmaf_rn( 2.f, a21, gy);
    gy = __fmaf_rn( 1.f, a22, gy);
    float s = __fadd_rn(__fmul_rn(gx, gx), __fmul_rn(gy, gy));
    float grad = (float)sqrt((double)s);
    const float THR = (float)(0.0789 + 1.0*0.0774);
    bool m = grad >= THR;
    u64 bits = __ballot(m);
    if ((threadIdx.x & 63) == 0) {
        int word = blockIdx.x*4 + (threadIdx.x >> 6);
        maskB[((size_t)b*H + y)*WPR + word] = bits;
    }
}

// ---------------- flood pass: 64-col x 768-row stripe in registers ----------------
__global__ __launch_bounds__(64) void floodColK(const u64* __restrict__ Mb,
                                                const u64* __restrict__ seedB,
                                                u64* __restrict__ Rb,
                                                unsigned* __restrict__ chg, int t) {
    if (t > 0 && chg[t-1] == 0) return;
    int b = blockIdx.y, wx = blockIdx.x, lane = threadIdx.x;
    const u64* M = Mb + (size_t)b*H*WPR;
    u64* R = Rb + (size_t)b*H*WPR;
    u64 m[12], r[12];
    #pragma unroll
    for (int j = 0; j < 12; j++) {
        int row = j*64 + lane;
        m[j] = M[row*WPR + wx];
        if (t == 0) r[j] = m[j] & seedB[((size_t)b*H + row)*WPR + wx];
        else        r[j] = R[row*WPR + wx];
    }
    unsigned cLmask = 0, cRmask = 0;
    {
        u64 CL[12], CR[12];
        #pragma unroll
        for (int j = 0; j < 12; j++) {
            int row = j*64 + lane;
            unsigned lv = 0, rv = 0;
            if (t > 0) {
                if (wx > 0)       lv = (unsigned)((R[row*WPR + wx - 1] >> 63) & 1ULL);
                if (wx < WPR - 1) rv = (unsigned)( R[row*WPR + wx + 1]        & 1ULL);
            }
            CL[j] = __ballot(lv != 0); CR[j] = __ballot(rv != 0);
        }
        #pragma unroll
        for (int j = 0; j < 12; j++) {
            u64 p = (j > 0)  ? CL[j-1] : 0ULL, n = (j < 11) ? CL[j+1] : 0ULL;
            u64 d = CL[j] | (CL[j] << 1) | (CL[j] >> 1) | (p >> 63) | (n << 63);
            cLmask |= (unsigned)((d >> lane) & 1ULL) << j;
            u64 p2 = (j > 0)  ? CR[j-1] : 0ULL, n2 = (j < 11) ? CR[j+1] : 0ULL;
            u64 d2 = CR[j] | (CR[j] << 1) | (CR[j] >> 1) | (p2 >> 63) | (n2 << 63);
            cRmask |= (unsigned)((d2 >> lane) & 1ULL) << j;
        }
    }
    bool grew = false;
    while (true) {
        bool any = false;
        #pragma unroll
        for (int j = 0; j < 12; j++) {
            u64 top = (j > 0)  ? __shfl(r[j-1], 63) : 0ULL;
            u64 bot = (j < 11) ? __shfl(r[j+1], 0)  : 0ULL;
            u64 up = __shfl_up(r[j], 1);   if (lane == 0)  up = top;
            u64 dn = __shfl_down(r[j], 1); if (lane == 63) dn = bot;
            u64 D = up | r[j] | dn;
            u64 nr = (D | (D << 1) | (D >> 1)
                      | (u64)((cLmask >> j) & 1u)
                      | ((u64)((cRmask >> j) & 1u) << 63)) & m[j];
            if (nr != r[j]) any = true;
            r[j] = nr;
        }
        if (!__any(any)) break;
        grew = true;
    }
    #pragma unroll
    for (int j = 0; j < 12; j++) R[(j*64 + lane)*WPR + wx] = r[j];
    if (__any(grew)) { if (lane == 0) atomicOr(&chg[t], 1u); }
}

// ---------------- final: out = (sigmoid?(pred)>0.5) | reach ----------------
__global__ void finalK(const float* __restrict__ pred, const u64* __restrict__ reachB,
                       const unsigned* __restrict__ sc, float* __restrict__ out) {
    int b = blockIdx.z, y = blockIdx.y, x = blockIdx.x*256 + threadIdx.x;
    float pmn = fdec(sc[16 + b]), pmx = fdec(sc[24 + b]);
    bool needSig = (pmx > 1.0f) || (pmn < 0.0f);
    float p = pred[((size_t)b*H + y)*W + x];
    float pv;
    if (needSig) {
        float e = (float)exp(-(double)p);
        pv = 1.f / (1.f + e);
    } else {
        pv = p;
    }
    bool on = pv > 0.5f;
    u64 w = reachB[((size_t)b*H + y)*WPR + (x >> 6)];
    on = on || ((w >> (x & 63)) & 1ULL);
    out[((size_t)b*H + y)*W + x] = on ? 1.f : 0.f;
}

extern "C" void kernel_launch(void* const* d_in, const int* in_sizes, int n_in,
                              void* d_out, int out_size, void* d_ws, size_t ws_size,
                              hipStream_t stream) {
    const float* pred = (const float*)d_in[0];
    const float* img  = (const float*)d_in[1];
    float* out = (float*)d_out;
    char* ws = (char*)d_ws;

    float*    wtab   = (float*)(ws + 1024);
    unsigned* sc     = (unsigned*)(ws + 16384);
    float*    fsum   = ((float*)sc) + 32;
    unsigned* chg    = sc + 64;
    float*    p12    = (float*)(ws + 20480);
    // bit buffers packed into plane area? no — keep separate region below 4 MiB:
    u64*      maskB  = (u64*)(ws + 1048576);              // 589,824 B
    u64*      seedB  = (u64*)(ws + 1048576 + 655360);     // 589,824 B
    u64*      reachB = (u64*)(ws + 1048576 + 1310720);    // 589,824 B  (ends < 4 MiB)
    const size_t PL = (size_t)NB*NP;                      // floats per plane
    float* plane = (float*)(ws + 4194304);
    float* b0  = plane;          // gauss tmp
    float* b1  = plane + PL;     // enh
    float* h0c = plane + 2*PL; float* h0s = plane + 3*PL;
    float* h1c = plane + 4*PL;
    float* h2c = plane + 5*PL; float* h2s = plane + 6*PL;
    float* h3c = plane + 7*PL;
    float* f0  = plane + 8*PL; float* f1 = plane + 9*PL;
    float* f2  = plane + 10*PL; float* f3 = plane + 11*PL;

    const float* gpadH = wtab;
    const float* gpadV = wtab + 128;

    initK<<<1, 256, 0, stream>>>(wtab, sc);
    reduceK<<<dim3(64, 8), 256, 0, stream>>>(img, pred, sc);

    dim3 gRow(768, 8);            // one image row per block (H passes)
    dim3 g3(3, H, 8);             // per-pixel kernels

    gaussHK2<<<gRow, 192, 0, stream>>>(img, b0, gpadH, sc);
    gaussVK4<<<2304, 128, 0, stream>>>(b0, img, b1, gpadV, sc);

    sobelK<<<g3, 256, 0, stream>>>(b1, maskB);

    gaborHF<<<gRow, 192, 0, stream>>>(b1, h0c, h0s, h1c, h2c, h2s, h3c, wtab);

    gaborV2pK<<<2304, 128, 0, stream>>>(h0c, h0s, f0, wtab + 768,  wtab + 896,  p12);
    sumK2<<<8, 256, 0, stream>>>(p12, fsum, 0);
    gaborV1pK<<<2304, 128, 0, stream>>>(h1c, f1, wtab + 1024, p12);
    sumK2<<<8, 256, 0, stream>>>(p12, fsum, 1);
    gaborV2pK<<<2304, 128, 0, stream>>>(h2c, h2s, f2, wtab + 1152, wtab + 1280, p12);
    sumK2<<<8, 256, 0, stream>>>(p12, fsum, 2);
    gaborV1pK<<<2304, 128, 0, stream>>>(h3c, f3, wtab + 1408, p12);
    sumK2<<<8, 256, 0, stream>>>(p12, fsum, 3);

    seedK3<<<g3, 256, 0, stream>>>(f0, f1, f2, f3, fsum, seedB);

    for (int t = 0; t < FLOOD_PASSES; t++)
        floodColK<<<dim3(12, 8), 64, 0, stream>>>(maskB, seedB, reachB, chg, t);
    finalK<<<g3, 256, 0, stream>>>(pred, reachB, sc, out);
}

// Round 5
// 331.258 us; speedup vs baseline: 2.8039x; 1.0128x over previous
//
#include <hip/hip_runtime.h>
#include <math.h>

typedef unsigned long long u64;

#define W 768
#define H 768
#define NP (768*768)
#define NB 8
#define WPR 12              // u64 words per row (768/64)
#define NW (NB*H*WPR)       // total words per bit buffer = 73728
#define FLOOD_PASSES 16
#define TH 16               // output rows per block in tiled vertical convs
#define P12N 73728          // floats per p12 angle region (8*768*12)

#define PADI(q) ((q) + ((q) >> 5))   // LDS pad: +1 word per 32

// ---------- ws layout (bytes) ----------
// 1024    : wtab (floats, 1536 entries):
//           [0..106] gpadH, [128..290] gpadV
//           [384+p*64]  6 uniform-17 horizontal tables (41 real entries):
//                p: 0=h0c 1=h0s 2=h1c 3=h2c 4=h2s 5=h3c
//           [768+q*128] 6 vertical tables (tap j at [31+j], zero-padded):
//                q: 0=v0c(R12) 1=v0s(R12) 2=v1c(R17) 3=v2c(R12) 4=v2s(R12) 5=v3c(R17)
// 16384   : sc (u32): [0..7] imgMinEnc [8..15] imgMaxEnc [16..23] predMinEnc
//           [24..31] predMaxEnc [32..63] fsum(f32) [64..127] changed
// 20480   : p12[4 angles][73728] f32  (1,179,648 B, ends 1,200,128)
// 1310720 : maskBits u64[NW] (589,824 B)
// 1900544 : seedBits u64[NW]
// 2490368 : reachBits u64[NW] (ends 3,080,192 < 4 MiB)
// 4 MiB   : 12 planes of 18,874,368 B:
//           0:b0(tmp) 1:b1(enh) 2:h0c 3:h0s 4:h1c 5:h2c 6:h2s 7:h3c 8:f0 9:f1 10:f2 11:f3

__device__ __forceinline__ unsigned fenc(float f) {
    unsigned b = __float_as_uint(f);
    return b ^ ((unsigned)((int)b >> 31) | 0x80000000u);
}
__device__ __forceinline__ float fdec(unsigned u) {
    unsigned b = (u & 0x80000000u) ? (u ^ 0x80000000u) : ~u;
    return __uint_as_float(b);
}
__device__ __forceinline__ int refl101(int i, int n) {
    if (i < 0) i = -i;
    if (i >= n) i = 2*n - 2 - i;
    return i;
}
__device__ __forceinline__ int symref(int i, int n) {
    if (i < 0) i = -1 - i;
    if (i >= n) i = 2*n - 1 - i;
    return i;
}

// ---------------- init: weight tables + scalar init ----------------
__global__ void initK(float* wtab, unsigned* sc) {
    int t = threadIdx.x;
    double sig = 15.5, ssum = 0.0;
    for (int i = 0; i < 101; i++) { double xx = i - 50; ssum += exp(-xx*xx/(2.0*sig*sig)); }
    for (int i = t; i < 107; i += 256) {        // gpadH: tap j at [3+j]
        float v = 0.f; int j = i - 3;
        if (j >= 0 && j < 101) { double xx = j - 50; v = (float)(exp(-xx*xx/(2.0*sig*sig))/ssum); }
        wtab[i] = v;
    }
    for (int i = t; i < 163; i += 256) {        // gpadV: tap j at [31+j]
        float v = 0.f; int j = i - 31;
        if (j >= 0 && j < 101) { double xx = j - 50; v = (float)(exp(-xx*xx/(2.0*sig*sig))/ssum); }
        wtab[128 + i] = v;
    }
    const double thetas[4] = {45.0, 90.0, 135.0, 180.0};
    const int    rad[4]    = {12, 17, 12, 17};
    const double sg = ((1.0/M_PI) * sqrt(log(2.0)/2.0) * 3.0) / 0.1;
    const double C  = 1.0/(2.0*M_PI*sg*sg);
    const int hG[6]   = {0, 0, 1, 2, 2, 3};
    const int hSin[6] = {0, 1, 0, 0, 1, 0};
    for (int idx = t; idx < 6*64; idx += 256) {
        int p = idx / 64, i = idx % 64;
        int g = hG[p], r = rad[g];
        double th = thetas[g] * (M_PI / 180.0);
        double a  = 2.0*M_PI*0.1*cos(th);
        float v = 0.f;
        int d = i - 20;
        if (i < 41 && d >= -r && d <= r) {
            double dd = (double)d, G = exp(-0.5*dd*dd/(sg*sg));
            v = hSin[p] ? (float)(C*G*sin(a*dd)) : (float)(C*G*cos(a*dd));
        }
        wtab[384 + p*64 + i] = v;
    }
    const int vG[6]   = {0, 0, 1, 2, 2, 3};
    const int vSin[6] = {0, 1, 0, 0, 1, 0};
    for (int idx = t; idx < 6*128; idx += 256) {
        int q = idx / 128, i = idx % 128;
        int g = vG[q], r = rad[g];
        double th = thetas[g] * (M_PI / 180.0);
        double bb = 2.0*M_PI*0.1*sin(th);
        float v = 0.f;
        int j = i - 31;
        if (j >= 0 && j <= 2*r) {
            double dd = (double)(j - r), G = exp(-0.5*dd*dd/(sg*sg));
            v = vSin[q] ? (float)(G*sin(bb*dd)) : (float)(G*cos(bb*dd));
        }
        wtab[768 + q*128 + i] = v;
    }
    if (t < 8)  { sc[t] = 0xFFFFFFFFu; sc[8+t] = 0u; sc[16+t] = 0xFFFFFFFFu; sc[24+t] = 0u; }
    if (t >= 32 && t < 64) ((float*)sc)[t] = 0.f;        // fsum
    if (t >= 64 && t < 128) sc[t] = (t == 64) ? 1u : 0u; // changed flags; chg[0]=1
}

// ---------------- per-image min/max of img and pred ----------------
__global__ void reduceK(const float* __restrict__ img, const float* __restrict__ pred,
                        unsigned* sc) {
    int b = blockIdx.y;
    int base = b*NP + blockIdx.x*9216 + threadIdx.x;
    float imn = INFINITY, imx = -INFINITY, pmn = INFINITY, pmx = -INFINITY;
    for (int k = 0; k < 36; k++) {
        float v = img[base + k*256];  imn = fminf(imn, v); imx = fmaxf(imx, v);
        float p = pred[base + k*256]; pmn = fminf(pmn, p); pmx = fmaxf(pmx, p);
    }
    for (int off = 32; off; off >>= 1) {
        imn = fminf(imn, __shfl_down(imn, off));
        imx = fmaxf(imx, __shfl_down(imx, off));
        pmn = fminf(pmn, __shfl_down(pmn, off));
        pmx = fmaxf(pmx, __shfl_down(pmx, off));
    }
    __shared__ float s[4][4];
    int lane = threadIdx.x & 63, wv = threadIdx.x >> 6;
    if (lane == 0) { s[0][wv] = imn; s[1][wv] = imx; s[2][wv] = pmn; s[3][wv] = pmx; }
    __syncthreads();
    if (threadIdx.x == 0) {
        float a0 = s[0][0], a1 = s[1][0], a2 = s[2][0], a3 = s[3][0];
        for (int w = 1; w < 4; w++) {
            a0 = fminf(a0, s[0][w]); a1 = fmaxf(a1, s[1][w]);
            a2 = fminf(a2, s[2][w]); a3 = fmaxf(a3, s[3][w]);
        }
        atomicMin(&sc[b],      fenc(a0));
        atomicMax(&sc[8 + b],  fenc(a1));
        atomicMin(&sc[16 + b], fenc(a2));
        atomicMax(&sc[24 + b], fenc(a3));
    }
}

// ---------------- Gaussian blur H: 4 outputs/thread, padded LDS ----------------
__global__ __launch_bounds__(192) void gaussHK2(const float* __restrict__ img,
                                                float* __restrict__ out,
                                                const float* __restrict__ wt,
                                                const unsigned* __restrict__ sc) {
    int b = blockIdx.y, y = blockIdx.x, t = threadIdx.x;
    float mn = fdec(sc[b]), mx = fdec(sc[8 + b]);
    float den = mx - mn;
    __shared__ float sh[896];
    const float* row = img + ((size_t)b*H + y)*W;
    for (int q = t; q < 868; q += 192) {
        int gx = refl101(q - 50, W);
        sh[PADI(q)] = (row[gx] - mn) / den;
    }
    __syncthreads();
    float a0 = 0.f, a1 = 0.f, a2 = 0.f, a3 = 0.f;
    int qb = 4*t;
    #pragma unroll
    for (int p = 0; p < 104; p++) {
        float v = sh[PADI(qb + p)];
        a0 = __fmaf_rn(wt[p + 3], v, a0);
        a1 = __fmaf_rn(wt[p + 2], v, a1);
        a2 = __fmaf_rn(wt[p + 1], v, a2);
        a3 = __fmaf_rn(wt[p    ], v, a3);
    }
    float4 o; o.x = a0; o.y = a1; o.z = a2; o.w = a3;
    *(float4*)(out + ((size_t)b*H + y)*W + qb) = o;
}

// ---------------- Gaussian blur V: unroll x4, XCD-resident image ----------------
__global__ __launch_bounds__(128) void gaussVK4(const float* __restrict__ tmp,
                                                const float* __restrict__ img,
                                                float* __restrict__ enh,
                                                const float* __restrict__ wt,
                                                const unsigned* __restrict__ sc) {
    int bid = blockIdx.x;
    int b = bid & 7; int r_ = bid >> 3; int tile = r_ % 48; int strip = r_ / 48;
    int y0 = tile*TH, x = strip*128 + threadIdx.x;
    float acc[TH];
    #pragma unroll
    for (int k = 0; k < TH; k++) acc[k] = 0.f;
    const float* T = tmp + (size_t)b*NP;
    for (int base = 0; base < 116; base += 4) {
        int g0 = refl101(y0+base-50, H), g1 = refl101(y0+base-49, H),
            g2 = refl101(y0+base-48, H), g3 = refl101(y0+base-47, H);
        float v0 = T[g0*W+x], v1 = T[g1*W+x], v2 = T[g2*W+x], v3 = T[g3*W+x];
        #pragma unroll
        for (int k = 0; k < TH; k++) {
            float a = acc[k];
            a = __fmaf_rn(wt[base   -k+31], v0, a);
            a = __fmaf_rn(wt[base+1 -k+31], v1, a);
            a = __fmaf_rn(wt[base+2 -k+31], v2, a);
            a = __fmaf_rn(wt[base+3 -k+31], v3, a);
            acc[k] = a;
        }
    }
    float mn = fdec(sc[b]), mx = fdec(sc[8 + b]);
    float den = mx - mn;
    #pragma unroll
    for (int k = 0; k < TH; k++) {
        size_t o = ((size_t)b*H + y0 + k)*W + x;
        float vv = (img[o] - mn) / den;
        float e = vv - acc[k];
        e = fminf(fmaxf(e, 0.f), 1.f);
        enh[o] = e;
    }
}

// ---------------- fused Gabor H: 6 planes in one pass ----------------
__global__ __launch_bounds__(192) void gaborHF(const float* __restrict__ enh,
        float* __restrict__ h0c, float* __restrict__ h0s, float* __restrict__ h1c,
        float* __restrict__ h2c, float* __restrict__ h2s, float* __restrict__ h3c,
        const float* __restrict__ wt) {
    int b = blockIdx.y, y = blockIdx.x, t = threadIdx.x;
    __shared__ float sh[832];
    const float* row = enh + ((size_t)b*H + y)*W;
    for (int q = t; q < 802; q += 192) {
        int gx = symref(q - 17, W);
        sh[PADI(q)] = row[gx];
    }
    __syncthreads();
    const float* T0c = wt + 384; const float* T0s = wt + 448; const float* T1c = wt + 512;
    const float* T2c = wt + 576; const float* T2s = wt + 640; const float* T3c = wt + 704;
    float a0c[4] = {0,0,0,0}, a0s[4] = {0,0,0,0}, a1c[4] = {0,0,0,0};
    float a2c[4] = {0,0,0,0}, a2s[4] = {0,0,0,0}, a3c[4] = {0,0,0,0};
    int qb = 4*t;
    #pragma unroll
    for (int p = 0; p < 38; p++) {
        float v = sh[PADI(qb + p)];
        #pragma unroll
        for (int sub = 0; sub < 4; sub++) {
            int idx = p + 3 - sub;
            a0c[sub] = __fmaf_rn(T0c[idx], v, a0c[sub]);
            a0s[sub] = __fmaf_rn(T0s[idx], v, a0s[sub]);
            a1c[sub] = __fmaf_rn(T1c[idx], v, a1c[sub]);
            a2c[sub] = __fmaf_rn(T2c[idx], v, a2c[sub]);
            a2s[sub] = __fmaf_rn(T2s[idx], v, a2s[sub]);
            a3c[sub] = __fmaf_rn(T3c[idx], v, a3c[sub]);
        }
    }
    size_t o = ((size_t)b*H + y)*W + qb;
    *(float4*)(h0c + o) = make_float4(a0c[0], a0c[1], a0c[2], a0c[3]);
    *(float4*)(h0s + o) = make_float4(a0s[0], a0s[1], a0s[2], a0s[3]);
    *(float4*)(h1c + o) = make_float4(a1c[0], a1c[1], a1c[2], a1c[3]);
    *(float4*)(h2c + o) = make_float4(a2c[0], a2c[1], a2c[2], a2c[3]);
    *(float4*)(h2s + o) = make_float4(a2s[0], a2s[1], a2s[2], a2s[3]);
    *(float4*)(h3c + o) = make_float4(a3c[0], a3c[1], a3c[2], a3c[3]);
}

// ---------------- fused Gabor V: 4 angles, uniform-17 window, unroll x2 ----------------
__global__ __launch_bounds__(128) void gaborVF(
        const float* __restrict__ h0c, const float* __restrict__ h0s,
        const float* __restrict__ h1c, const float* __restrict__ h2c,
        const float* __restrict__ h2s, const float* __restrict__ h3c,
        float* __restrict__ f0, float* __restrict__ f1,
        float* __restrict__ f2, float* __restrict__ f3,
        const float* __restrict__ wt, float* __restrict__ p12) {
    int bid = blockIdx.x;
    int b = bid & 7; int r_ = bid >> 3; int tile = r_ % 48; int strip = r_ / 48;
    int y0 = tile*TH, x = strip*128 + threadIdx.x;
    const float* T0c = wt + 768;  const float* T0s = wt + 896;
    const float* T1c = wt + 1024;
    const float* T2c = wt + 1152; const float* T2s = wt + 1280;
    const float* T3c = wt + 1408;
    float a0[TH], a1[TH], a2[TH], a3[TH];
    #pragma unroll
    for (int k = 0; k < TH; k++) { a0[k] = 0.f; a1[k] = 0.f; a2[k] = 0.f; a3[k] = 0.f; }
    const size_t pb = (size_t)b*NP;
    for (int base = 0; base < 50; base += 2) {
        int gA = symref(y0 + base - 17, H), gB = symref(y0 + base - 16, H);
        size_t oA = pb + (size_t)gA*W + x, oB = pb + (size_t)gB*W + x;
        float v0cA = h0c[oA], v0sA = h0s[oA], v1cA = h1c[oA];
        float v2cA = h2c[oA], v2sA = h2s[oA], v3cA = h3c[oA];
        float v0cB = h0c[oB], v0sB = h0s[oB], v1cB = h1c[oB];
        float v2cB = h2c[oB], v2sB = h2s[oB], v3cB = h3c[oB];
        #pragma unroll
        for (int k = 0; k < TH; k++) {
            int i26 = base - k + 26, i31 = base - k + 31;
            float t;
            t = a0[k];
            t = __fmaf_rn( T0c[i26],   v0cA, t); t = __fmaf_rn(-T0s[i26],   v0sA, t);
            t = __fmaf_rn( T0c[i26+1], v0cB, t); t = __fmaf_rn(-T0s[i26+1], v0sB, t);
            a0[k] = t;
            t = a1[k];
            t = __fmaf_rn( T1c[i31],   v1cA, t);
            t = __fmaf_rn( T1c[i31+1], v1cB, t);
            a1[k] = t;
            t = a2[k];
            t = __fmaf_rn( T2c[i26],   v2cA, t); t = __fmaf_rn(-T2s[i26],   v2sA, t);
            t = __fmaf_rn( T2c[i26+1], v2cB, t); t = __fmaf_rn(-T2s[i26+1], v2sB, t);
            a2[k] = t;
            t = a3[k];
            t = __fmaf_rn( T3c[i31],   v3cA, t);
            t = __fmaf_rn( T3c[i31+1], v3cB, t);
            a3[k] = t;
        }
    }
    int g64 = strip*2 + (threadIdx.x >> 6);
    bool l0 = (threadIdx.x & 63) == 0;
    #pragma unroll
    for (int k = 0; k < TH; k++) {
        size_t o = ((size_t)b*H + y0 + k)*W + x;
        size_t po = ((size_t)b*H + y0 + k)*12 + g64;
        f0[o] = a0[k];
        float s = a0[k];
        for (int off = 32; off; off >>= 1) s += __shfl_down(s, off);
        if (l0) p12[po] = s;
        f1[o] = a1[k];
        s = a1[k];
        for (int off = 32; off; off >>= 1) s += __shfl_down(s, off);
        if (l0) p12[P12N + po] = s;
        f2[o] = a2[k];
        s = a2[k];
        for (int off = 32; off; off >>= 1) s += __shfl_down(s, off);
        if (l0) p12[2*P12N + po] = s;
        f3[o] = a3[k];
        s = a3[k];
        for (int off = 32; off; off >>= 1) s += __shfl_down(s, off);
        if (l0) p12[3*P12N + po] = s;
    }
}

// ---------------- deterministic per-image sums, all 4 angles ----------------
__global__ void sumKAll(const float* __restrict__ p12, float* fsum) {
    int b = blockIdx.x, g = blockIdx.y, t = threadIdx.x;
    const float* P = p12 + (size_t)g*P12N;
    float s = 0.f;
    for (int k = 0; k < 9; k++) {
        int idx = t + k*256;                 // 0..2303 == row*3 + strip
        int row = idx / 3, strip = idx - row*3;
        const float* Q = P + ((size_t)b*H + row)*12 + strip*4;
        float p4 = ((Q[0] + Q[1]) + Q[2]) + Q[3];
        s += p4;
    }
    __shared__ float sm[256];
    sm[t] = s; __syncthreads();
    for (int off = 128; off; off >>= 1) {
        if (t < off) sm[t] += sm[t + off];
        __syncthreads();
    }
    if (t == 0) fsum[g*8 + b] = sm[0];
}

// ---------------- seeds: row-tiled, 4 planes sequential in LDS ----------------
__global__ __launch_bounds__(256) void seedK4(const float* __restrict__ f0,
        const float* __restrict__ f1, const float* __restrict__ f2,
        const float* __restrict__ f3, const float* __restrict__ fsum,
        u64* __restrict__ seedB) {
    int b = blockIdx.z, y0 = blockIdx.y*16, x0 = blockIdx.x*256, t = threadIdx.x;
    __shared__ float sh[18][258];
    const float* planes[4] = {f0, f1, f2, f3};
    unsigned condMask = 0;
    #pragma unroll
    for (int a = 0; a < 4; a++) {
        const float* F = planes[a] + (size_t)b*NP;
        __syncthreads();
        for (int idx = t; idx < 18*258; idx += 256) {
            int rr = idx / 258, q = idx - rr*258;
            int gy = y0 - 1 + rr; gy = gy < 0 ? 0 : (gy > H-1 ? H-1 : gy);
            int gx = x0 - 1 + q;  gx = gx < 0 ? 0 : (gx > W-1 ? W-1 : gx);
            sh[rr][q] = F[gy*W + gx];
        }
        __syncthreads();
        float mean = fsum[a*8 + b] / 589824.f;
        #pragma unroll
        for (int r = 0; r < 16; r++) {
            float c = sh[r+1][t+1];
            float mx = c;
            mx = fmaxf(mx, sh[r  ][t]); mx = fmaxf(mx, sh[r  ][t+1]); mx = fmaxf(mx, sh[r  ][t+2]);
            mx = fmaxf(mx, sh[r+1][t]); mx = fmaxf(mx, sh[r+1][t+1]); mx = fmaxf(mx, sh[r+1][t+2]);
            mx = fmaxf(mx, sh[r+2][t]); mx = fmaxf(mx, sh[r+2][t+1]); mx = fmaxf(mx, sh[r+2][t+2]);
            if ((c == mx) && (c > mean)) condMask |= (1u << r);
        }
    }
    int wv = t >> 6, lane = t & 63;
    #pragma unroll
    for (int r = 0; r < 16; r++) {
        u64 m = __ballot((condMask >> r) & 1u);
        if (lane == 0)
            seedB[((size_t)b*H + y0 + r)*WPR + blockIdx.x*4 + wv] = m;
    }
}

// ---------------- Sobel grad mask (bitpacked) ----------------
__global__ void sobelK(const float* __restrict__ enh, u64* __restrict__ maskB) {
    int b = blockIdx.z, y = blockIdx.y, x = blockIdx.x*256 + threadIdx.x;
    const float* E = enh + (size_t)b*NP;
    int ym = y > 0 ? y-1 : 1, yp = y < H-1 ? y+1 : H-2;   // reflect101
    int xm = x > 0 ? x-1 : 1, xp = x < W-1 ? x+1 : W-2;
    float a00 = E[ym*W + xm], a01 = E[ym*W + x], a02 = E[ym*W + xp];
    float a10 = E[y*W + xm],                     a12 = E[y*W + xp];
    float a20 = E[yp*W + xm], a21 = E[yp*W + x], a22 = E[yp*W + xp];
    float gx = __fmaf_rn(-1.f, a00, 0.f);
    gx = __fmaf_rn( 1.f, a02, gx);
    gx = __fmaf_rn(-2.f, a10, gx);
    gx = __fmaf_rn( 2.f, a12, gx);
    gx = __fmaf_rn(-1.f, a20, gx);
    gx = __fmaf_rn( 1.f, a22, gx);
    float gy = __fmaf_rn(-1.f, a00, 0.f);
    gy = __fmaf_rn(-2.f, a01, gy);
    gy = __fmaf_rn(-1.f, a02, gy);
    gy = __fmaf_rn( 1.f, a20, gy);
    gy = __fmaf_rn( 2.f, a21, gy);
    gy = __fmaf_rn( 1.f, a22, gy);
    float s = __fadd_rn(__fmul_rn(gx, gx), __fmul_rn(gy, gy));
    float grad = (float)sqrt((double)s);
    const float THR = (float)(0.0789 + 1.0*0.0774);
    bool m = grad >= THR;
    u64 bits = __ballot(m);
    if ((threadIdx.x & 63) == 0) {
        int word = blockIdx.x*4 + (threadIdx.x >> 6);
        maskB[((size_t)b*H + y)*WPR + word] = bits;
    }
}

// ---------------- flood pass: 64-col x 768-row stripe in registers ----------------
__global__ __launch_bounds__(64) void floodColK(const u64* __restrict__ Mb,
                                                const u64* __restrict__ seedB,
                                                u64* __restrict__ Rb,
                                                unsigned* __restrict__ chg, int t) {
    if (t > 0 && chg[t-1] == 0) return;
    int b = blockIdx.y, wx = blockIdx.x, lane = threadIdx.x;
    const u64* M = Mb + (size_t)b*H*WPR;
    u64* R = Rb + (size_t)b*H*WPR;
    u64 m[12], r[12];
    #pragma unroll
    for (int j = 0; j < 12; j++) {
        int row = j*64 + lane;
        m[j] = M[row*WPR + wx];
        if (t == 0) r[j] = m[j] & seedB[((size_t)b*H + row)*WPR + wx];
        else        r[j] = R[row*WPR + wx];
    }
    unsigned cLmask = 0, cRmask = 0;
    {
        u64 CL[12], CR[12];
        #pragma unroll
        for (int j = 0; j < 12; j++) {
            int row = j*64 + lane;
            unsigned lv = 0, rv = 0;
            if (t > 0) {
                if (wx > 0)       lv = (unsigned)((R[row*WPR + wx - 1] >> 63) & 1ULL);
                if (wx < WPR - 1) rv = (unsigned)( R[row*WPR + wx + 1]        & 1ULL);
            }
            CL[j] = __ballot(lv != 0); CR[j] = __ballot(rv != 0);
        }
        #pragma unroll
        for (int j = 0; j < 12; j++) {
            u64 p = (j > 0)  ? CL[j-1] : 0ULL, n = (j < 11) ? CL[j+1] : 0ULL;
            u64 d = CL[j] | (CL[j] << 1) | (CL[j] >> 1) | (p >> 63) | (n << 63);
            cLmask |= (unsigned)((d >> lane) & 1ULL) << j;
            u64 p2 = (j > 0)  ? CR[j-1] : 0ULL, n2 = (j < 11) ? CR[j+1] : 0ULL;
            u64 d2 = CR[j] | (CR[j] << 1) | (CR[j] >> 1) | (p2 >> 63) | (n2 << 63);
            cRmask |= (unsigned)((d2 >> lane) & 1ULL) << j;
        }
    }
    bool grew = false;
    while (true) {
        bool any = false;
        #pragma unroll
        for (int j = 0; j < 12; j++) {
            u64 top = (j > 0)  ? __shfl(r[j-1], 63) : 0ULL;
            u64 bot = (j < 11) ? __shfl(r[j+1], 0)  : 0ULL;
            u64 up = __shfl_up(r[j], 1);   if (lane == 0)  up = top;
            u64 dn = __shfl_down(r[j], 1); if (lane == 63) dn = bot;
            u64 D = up | r[j] | dn;
            u64 nr = (D | (D << 1) | (D >> 1)
                      | (u64)((cLmask >> j) & 1u)
                      | ((u64)((cRmask >> j) & 1u) << 63)) & m[j];
            if (nr != r[j]) any = true;
            r[j] = nr;
        }
        if (!__any(any)) break;
        grew = true;
    }
    #pragma unroll
    for (int j = 0; j < 12; j++) R[(j*64 + lane)*WPR + wx] = r[j];
    if (__any(grew)) { if (lane == 0) atomicOr(&chg[t], 1u); }
}

// ---------------- final: out = (sigmoid?(pred)>0.5) | reach ----------------
__global__ void finalK(const float* __restrict__ pred, const u64* __restrict__ reachB,
                       const unsigned* __restrict__ sc, float* __restrict__ out) {
    int b = blockIdx.z, y = blockIdx.y, x = blockIdx.x*256 + threadIdx.x;
    float pmn = fdec(sc[16 + b]), pmx = fdec(sc[24 + b]);
    bool needSig = (pmx > 1.0f) || (pmn < 0.0f);
    float p = pred[((size_t)b*H + y)*W + x];
    float pv;
    if (needSig) {
        float e = (float)exp(-(double)p);
        pv = 1.f / (1.f + e);
    } else {
        pv = p;
    }
    bool on = pv > 0.5f;
    u64 w = reachB[((size_t)b*H + y)*WPR + (x >> 6)];
    on = on || ((w >> (x & 63)) & 1ULL);
    out[((size_t)b*H + y)*W + x] = on ? 1.f : 0.f;
}

extern "C" void kernel_launch(void* const* d_in, const int* in_sizes, int n_in,
                              void* d_out, int out_size, void* d_ws, size_t ws_size,
                              hipStream_t stream) {
    const float* pred = (const float*)d_in[0];
    const float* img  = (const float*)d_in[1];
    float* out = (float*)d_out;
    char* ws = (char*)d_ws;

    float*    wtab   = (float*)(ws + 1024);
    unsigned* sc     = (unsigned*)(ws + 16384);
    float*    fsum   = ((float*)sc) + 32;
    unsigned* chg    = sc + 64;
    float*    p12    = (float*)(ws + 20480);
    u64*      maskB  = (u64*)(ws + 1310720);
    u64*      seedB  = (u64*)(ws + 1900544);
    u64*      reachB = (u64*)(ws + 2490368);
    const size_t PL = (size_t)NB*NP;                      // floats per plane
    float* plane = (float*)(ws + 4194304);
    float* b0  = plane;          // gauss tmp
    float* b1  = plane + PL;     // enh
    float* h0c = plane + 2*PL; float* h0s = plane + 3*PL;
    float* h1c = plane + 4*PL;
    float* h2c = plane + 5*PL; float* h2s = plane + 6*PL;
    float* h3c = plane + 7*PL;
    float* f0  = plane + 8*PL; float* f1 = plane + 9*PL;
    float* f2  = plane + 10*PL; float* f3 = plane + 11*PL;

    const float* gpadH = wtab;
    const float* gpadV = wtab + 128;

    initK<<<1, 256, 0, stream>>>(wtab, sc);
    reduceK<<<dim3(64, 8), 256, 0, stream>>>(img, pred, sc);

    dim3 gRow(768, 8);            // one image row per block (H passes)
    dim3 g3(3, H, 8);             // per-pixel kernels

    gaussHK2<<<gRow, 192, 0, stream>>>(img, b0, gpadH, sc);
    gaussVK4<<<2304, 128, 0, stream>>>(b0, img, b1, gpadV, sc);

    sobelK<<<g3, 256, 0, stream>>>(b1, maskB);

    gaborHF<<<gRow, 192, 0, stream>>>(b1, h0c, h0s, h1c, h2c, h2s, h3c, wtab);

    gaborVF<<<2304, 128, 0, stream>>>(h0c, h0s, h1c, h2c, h2s, h3c,
                                      f0, f1, f2, f3, wtab, p12);
    sumKAll<<<dim3(8, 4), 256, 0, stream>>>(p12, fsum);

    seedK4<<<dim3(3, 48, 8), 256, 0, stream>>>(f0, f1, f2, f3, fsum, seedB);

    for (int t = 0; t < FLOOD_PASSES; t++)
        floodColK<<<dim3(12, 8), 64, 0, stream>>>(maskB, seedB, reachB, chg, t);
    finalK<<<g3, 256, 0, stream>>>(pred, reachB, sc, out);
}

// Round 6
// 314.742 us; speedup vs baseline: 2.9511x; 1.0525x over previous
//
#include <hip/hip_runtime.h>
#include <math.h>

typedef unsigned long long u64;

#define W 768
#define H 768
#define NP (768*768)
#define NB 8
#define WPR 12              // u64 words per row (768/64)
#define NW (NB*H*WPR)       // total words per bit buffer = 73728
#define FLOOD_PASSES 16
#define TH 16               // output rows per block in tiled vertical convs
#define P12N 73728          // floats per p12 angle region (8*768*12)

#define PADI(q) ((q) + ((q) >> 5))   // LDS pad: +1 word per 32

// ---------- ws layout (bytes) ----------
// 1024    : wtab (floats, 1536 entries):
//           [0..106] gpadH, [128..290] gpadV
//           [384+p*64]  6 uniform-17 horizontal tables (41 real entries):
//                p: 0=h0c 1=h0s 2=h1c 3=h2c 4=h2s 5=h3c
//           [768+q*128] 6 vertical tables (tap j at [31+j], zero-padded):
//                q: 0=v0c(R12) 1=v0s(R12) 2=v1c(R17) 3=v2c(R12) 4=v2s(R12) 5=v3c(R17)
// 16384   : sc (u32): [0..7] imgMinEnc [8..15] imgMaxEnc [16..23] predMinEnc
//           [24..31] predMaxEnc [32..63] fsum(f32) [64..127] changed
// 20480   : p12[4 angles][73728] f32  (1,179,648 B, ends 1,200,128)
// 1310720 : maskBits u64[NW] (589,824 B)
// 1900544 : seedBits u64[NW]
// 2490368 : reachBits u64[NW] (ends 3,080,192 < 4 MiB)
// 4 MiB   : 12 planes of 18,874,368 B:
//           0:b0(tmp) 1:b1(enh) 2:h0c 3:h0s 4:h1c 5:h2c 6:h2s 7:h3c 8:f0 9:f1 10:f2 11:f3

__device__ __forceinline__ unsigned fenc(float f) {
    unsigned b = __float_as_uint(f);
    return b ^ ((unsigned)((int)b >> 31) | 0x80000000u);
}
__device__ __forceinline__ float fdec(unsigned u) {
    unsigned b = (u & 0x80000000u) ? (u ^ 0x80000000u) : ~u;
    return __uint_as_float(b);
}
__device__ __forceinline__ int refl101(int i, int n) {
    if (i < 0) i = -i;
    if (i >= n) i = 2*n - 2 - i;
    return i;
}
__device__ __forceinline__ int symref(int i, int n) {
    if (i < 0) i = -1 - i;
    if (i >= n) i = 2*n - 1 - i;
    return i;
}

// ---------------- init: weight tables + scalar init ----------------
__global__ void initK(float* wtab, unsigned* sc) {
    int t = threadIdx.x;
    double sig = 15.5, ssum = 0.0;
    for (int i = 0; i < 101; i++) { double xx = i - 50; ssum += exp(-xx*xx/(2.0*sig*sig)); }
    for (int i = t; i < 107; i += 256) {        // gpadH: tap j at [3+j]
        float v = 0.f; int j = i - 3;
        if (j >= 0 && j < 101) { double xx = j - 50; v = (float)(exp(-xx*xx/(2.0*sig*sig))/ssum); }
        wtab[i] = v;
    }
    for (int i = t; i < 163; i += 256) {        // gpadV: tap j at [31+j]
        float v = 0.f; int j = i - 31;
        if (j >= 0 && j < 101) { double xx = j - 50; v = (float)(exp(-xx*xx/(2.0*sig*sig))/ssum); }
        wtab[128 + i] = v;
    }
    const double thetas[4] = {45.0, 90.0, 135.0, 180.0};
    const int    rad[4]    = {12, 17, 12, 17};
    const double sg = ((1.0/M_PI) * sqrt(log(2.0)/2.0) * 3.0) / 0.1;
    const double C  = 1.0/(2.0*M_PI*sg*sg);
    const int hG[6]   = {0, 0, 1, 2, 2, 3};
    const int hSin[6] = {0, 1, 0, 0, 1, 0};
    for (int idx = t; idx < 6*64; idx += 256) {
        int p = idx / 64, i = idx % 64;
        int g = hG[p], r = rad[g];
        double th = thetas[g] * (M_PI / 180.0);
        double a  = 2.0*M_PI*0.1*cos(th);
        float v = 0.f;
        int d = i - 20;
        if (i < 41 && d >= -r && d <= r) {
            double dd = (double)d, G = exp(-0.5*dd*dd/(sg*sg));
            v = hSin[p] ? (float)(C*G*sin(a*dd)) : (float)(C*G*cos(a*dd));
        }
        wtab[384 + p*64 + i] = v;
    }
    const int vG[6]   = {0, 0, 1, 2, 2, 3};
    const int vSin[6] = {0, 1, 0, 0, 1, 0};
    for (int idx = t; idx < 6*128; idx += 256) {
        int q = idx / 128, i = idx % 128;
        int g = vG[q], r = rad[g];
        double th = thetas[g] * (M_PI / 180.0);
        double bb = 2.0*M_PI*0.1*sin(th);
        float v = 0.f;
        int j = i - 31;
        if (j >= 0 && j <= 2*r) {
            double dd = (double)(j - r), G = exp(-0.5*dd*dd/(sg*sg));
            v = vSin[q] ? (float)(G*sin(bb*dd)) : (float)(G*cos(bb*dd));
        }
        wtab[768 + q*128 + i] = v;
    }
    if (t < 8)  { sc[t] = 0xFFFFFFFFu; sc[8+t] = 0u; sc[16+t] = 0xFFFFFFFFu; sc[24+t] = 0u; }
    if (t >= 32 && t < 64) ((float*)sc)[t] = 0.f;        // fsum
    if (t >= 64 && t < 128) sc[t] = (t == 64) ? 1u : 0u; // changed flags; chg[0]=1
}

// ---------------- per-image min/max of img and pred ----------------
__global__ void reduceK(const float* __restrict__ img, const float* __restrict__ pred,
                        unsigned* sc) {
    int b = blockIdx.y;
    int base = b*NP + blockIdx.x*9216 + threadIdx.x;
    float imn = INFINITY, imx = -INFINITY, pmn = INFINITY, pmx = -INFINITY;
    for (int k = 0; k < 36; k++) {
        float v = img[base + k*256];  imn = fminf(imn, v); imx = fmaxf(imx, v);
        float p = pred[base + k*256]; pmn = fminf(pmn, p); pmx = fmaxf(pmx, p);
    }
    for (int off = 32; off; off >>= 1) {
        imn = fminf(imn, __shfl_down(imn, off));
        imx = fmaxf(imx, __shfl_down(imx, off));
        pmn = fminf(pmn, __shfl_down(pmn, off));
        pmx = fmaxf(pmx, __shfl_down(pmx, off));
    }
    __shared__ float s[4][4];
    int lane = threadIdx.x & 63, wv = threadIdx.x >> 6;
    if (lane == 0) { s[0][wv] = imn; s[1][wv] = imx; s[2][wv] = pmn; s[3][wv] = pmx; }
    __syncthreads();
    if (threadIdx.x == 0) {
        float a0 = s[0][0], a1 = s[1][0], a2 = s[2][0], a3 = s[3][0];
        for (int w = 1; w < 4; w++) {
            a0 = fminf(a0, s[0][w]); a1 = fmaxf(a1, s[1][w]);
            a2 = fminf(a2, s[2][w]); a3 = fmaxf(a3, s[3][w]);
        }
        atomicMin(&sc[b],      fenc(a0));
        atomicMax(&sc[8 + b],  fenc(a1));
        atomicMin(&sc[16 + b], fenc(a2));
        atomicMax(&sc[24 + b], fenc(a3));
    }
}

// ---------------- Gaussian blur H: 4 outputs/thread, padded LDS ----------------
__global__ __launch_bounds__(192) void gaussHK2(const float* __restrict__ img,
                                                float* __restrict__ out,
                                                const float* __restrict__ wt,
                                                const unsigned* __restrict__ sc) {
    int b = blockIdx.y, y = blockIdx.x, t = threadIdx.x;
    float mn = fdec(sc[b]), mx = fdec(sc[8 + b]);
    float den = mx - mn;
    __shared__ float sh[896];
    const float* row = img + ((size_t)b*H + y)*W;
    for (int q = t; q < 868; q += 192) {
        int gx = refl101(q - 50, W);
        sh[PADI(q)] = (row[gx] - mn) / den;
    }
    __syncthreads();
    float a0 = 0.f, a1 = 0.f, a2 = 0.f, a3 = 0.f;
    int qb = 4*t;
    #pragma unroll
    for (int p = 0; p < 104; p++) {
        float v = sh[PADI(qb + p)];
        a0 = __fmaf_rn(wt[p + 3], v, a0);
        a1 = __fmaf_rn(wt[p + 2], v, a1);
        a2 = __fmaf_rn(wt[p + 1], v, a2);
        a3 = __fmaf_rn(wt[p    ], v, a3);
    }
    float4 o; o.x = a0; o.y = a1; o.z = a2; o.w = a3;
    *(float4*)(out + ((size_t)b*H + y)*W + qb) = o;
}

// ---------------- Gaussian blur V: unroll x4, XCD-resident image ----------------
__global__ __launch_bounds__(128) void gaussVK4(const float* __restrict__ tmp,
                                                const float* __restrict__ img,
                                                float* __restrict__ enh,
                                                const float* __restrict__ wt,
                                                const unsigned* __restrict__ sc) {
    int bid = blockIdx.x;
    int b = bid & 7; int r_ = bid >> 3; int tile = r_ % 48; int strip = r_ / 48;
    int y0 = tile*TH, x = strip*128 + threadIdx.x;
    float acc[TH];
    #pragma unroll
    for (int k = 0; k < TH; k++) acc[k] = 0.f;
    const float* T = tmp + (size_t)b*NP;
    for (int base = 0; base < 116; base += 4) {
        int g0 = refl101(y0+base-50, H), g1 = refl101(y0+base-49, H),
            g2 = refl101(y0+base-48, H), g3 = refl101(y0+base-47, H);
        float v0 = T[g0*W+x], v1 = T[g1*W+x], v2 = T[g2*W+x], v3 = T[g3*W+x];
        #pragma unroll
        for (int k = 0; k < TH; k++) {
            float a = acc[k];
            a = __fmaf_rn(wt[base   -k+31], v0, a);
            a = __fmaf_rn(wt[base+1 -k+31], v1, a);
            a = __fmaf_rn(wt[base+2 -k+31], v2, a);
            a = __fmaf_rn(wt[base+3 -k+31], v3, a);
            acc[k] = a;
        }
    }
    float mn = fdec(sc[b]), mx = fdec(sc[8 + b]);
    float den = mx - mn;
    #pragma unroll
    for (int k = 0; k < TH; k++) {
        size_t o = ((size_t)b*H + y0 + k)*W + x;
        float vv = (img[o] - mn) / den;
        float e = vv - acc[k];
        e = fminf(fmaxf(e, 0.f), 1.f);
        enh[o] = e;
    }
}

// ---------------- fused Gabor H: 6 planes in one pass ----------------
__global__ __launch_bounds__(192) void gaborHF(const float* __restrict__ enh,
        float* __restrict__ h0c, float* __restrict__ h0s, float* __restrict__ h1c,
        float* __restrict__ h2c, float* __restrict__ h2s, float* __restrict__ h3c,
        const float* __restrict__ wt) {
    int b = blockIdx.y, y = blockIdx.x, t = threadIdx.x;
    __shared__ float sh[832];
    const float* row = enh + ((size_t)b*H + y)*W;
    for (int q = t; q < 802; q += 192) {
        int gx = symref(q - 17, W);
        sh[PADI(q)] = row[gx];
    }
    __syncthreads();
    const float* T0c = wt + 384; const float* T0s = wt + 448; const float* T1c = wt + 512;
    const float* T2c = wt + 576; const float* T2s = wt + 640; const float* T3c = wt + 704;
    float a0c[4] = {0,0,0,0}, a0s[4] = {0,0,0,0}, a1c[4] = {0,0,0,0};
    float a2c[4] = {0,0,0,0}, a2s[4] = {0,0,0,0}, a3c[4] = {0,0,0,0};
    int qb = 4*t;
    #pragma unroll
    for (int p = 0; p < 38; p++) {
        float v = sh[PADI(qb + p)];
        #pragma unroll
        for (int sub = 0; sub < 4; sub++) {
            int idx = p + 3 - sub;
            a0c[sub] = __fmaf_rn(T0c[idx], v, a0c[sub]);
            a0s[sub] = __fmaf_rn(T0s[idx], v, a0s[sub]);
            a1c[sub] = __fmaf_rn(T1c[idx], v, a1c[sub]);
            a2c[sub] = __fmaf_rn(T2c[idx], v, a2c[sub]);
            a2s[sub] = __fmaf_rn(T2s[idx], v, a2s[sub]);
            a3c[sub] = __fmaf_rn(T3c[idx], v, a3c[sub]);
        }
    }
    size_t o = ((size_t)b*H + y)*W + qb;
    *(float4*)(h0c + o) = make_float4(a0c[0], a0c[1], a0c[2], a0c[3]);
    *(float4*)(h0s + o) = make_float4(a0s[0], a0s[1], a0s[2], a0s[3]);
    *(float4*)(h1c + o) = make_float4(a1c[0], a1c[1], a1c[2], a1c[3]);
    *(float4*)(h2c + o) = make_float4(a2c[0], a2c[1], a2c[2], a2c[3]);
    *(float4*)(h2s + o) = make_float4(a2s[0], a2s[1], a2s[2], a2s[3]);
    *(float4*)(h3c + o) = make_float4(a3c[0], a3c[1], a3c[2], a3c[3]);
}

// ------- Gabor V half: one 2-plane angle (R12) + one 1-plane angle (R17) -------
// Chains per accumulator identical to the round-5 passing gaborVF.
__global__ __launch_bounds__(128) void gaborV2(
        const float* __restrict__ hcA, const float* __restrict__ hsA,
        const float* __restrict__ hcB,
        float* __restrict__ fA, float* __restrict__ fB,
        const float* __restrict__ TcA, const float* __restrict__ TsA,
        const float* __restrict__ TcB,
        float* __restrict__ pA, float* __restrict__ pB) {
    int bid = blockIdx.x;
    int b = bid & 7; int r_ = bid >> 3; int tile = r_ % 48; int strip = r_ / 48;
    int y0 = tile*TH, x = strip*128 + threadIdx.x;
    float a0[TH], a1[TH];
    #pragma unroll
    for (int k = 0; k < TH; k++) { a0[k] = 0.f; a1[k] = 0.f; }
    const size_t pb = (size_t)b*NP;
    for (int base = 0; base < 50; base += 2) {
        int gA = symref(y0 + base - 17, H), gB = symref(y0 + base - 16, H);
        size_t oA = pb + (size_t)gA*W + x, oB = pb + (size_t)gB*W + x;
        float vcA = hcA[oA], vsA = hsA[oA], vbA = hcB[oA];
        float vcB = hcA[oB], vsB = hsA[oB], vbB = hcB[oB];
        #pragma unroll
        for (int k = 0; k < TH; k++) {
            int i26 = base - k + 26, i31 = base - k + 31;
            float t;
            t = a0[k];
            t = __fmaf_rn( TcA[i26],   vcA, t); t = __fmaf_rn(-TsA[i26],   vsA, t);
            t = __fmaf_rn( TcA[i26+1], vcB, t); t = __fmaf_rn(-TsA[i26+1], vsB, t);
            a0[k] = t;
            t = a1[k];
            t = __fmaf_rn( TcB[i31],   vbA, t);
            t = __fmaf_rn( TcB[i31+1], vbB, t);
            a1[k] = t;
        }
    }
    int g64 = strip*2 + (threadIdx.x >> 6);
    bool l0 = (threadIdx.x & 63) == 0;
    #pragma unroll
    for (int k = 0; k < TH; k++) {
        size_t o = ((size_t)b*H + y0 + k)*W + x;
        size_t po = ((size_t)b*H + y0 + k)*12 + g64;
        fA[o] = a0[k];
        float s = a0[k];
        for (int off = 32; off; off >>= 1) s += __shfl_down(s, off);
        if (l0) pA[po] = s;
        fB[o] = a1[k];
        s = a1[k];
        for (int off = 32; off; off >>= 1) s += __shfl_down(s, off);
        if (l0) pB[po] = s;
    }
}

// ---------------- deterministic per-image sums, all 4 angles ----------------
__global__ void sumKAll(const float* __restrict__ p12, float* fsum) {
    int b = blockIdx.x, g = blockIdx.y, t = threadIdx.x;
    const float* P = p12 + (size_t)g*P12N;
    float s = 0.f;
    for (int k = 0; k < 9; k++) {
        int idx = t + k*256;                 // 0..2303 == row*3 + strip
        int row = idx / 3, strip = idx - row*3;
        const float* Q = P + ((size_t)b*H + row)*12 + strip*4;
        float p4 = ((Q[0] + Q[1]) + Q[2]) + Q[3];
        s += p4;
    }
    __shared__ float sm[256];
    sm[t] = s; __syncthreads();
    for (int off = 128; off; off >>= 1) {
        if (t < off) sm[t] += sm[t + off];
        __syncthreads();
    }
    if (t == 0) fsum[g*8 + b] = sm[0];
}

// ---------------- seeds: row-tiled, 4 planes sequential in LDS ----------------
__global__ __launch_bounds__(256) void seedK4(const float* __restrict__ f0,
        const float* __restrict__ f1, const float* __restrict__ f2,
        const float* __restrict__ f3, const float* __restrict__ fsum,
        u64* __restrict__ seedB) {
    int b = blockIdx.z, y0 = blockIdx.y*16, x0 = blockIdx.x*256, t = threadIdx.x;
    __shared__ float sh[18][258];
    const float* planes[4] = {f0, f1, f2, f3};
    unsigned condMask = 0;
    #pragma unroll
    for (int a = 0; a < 4; a++) {
        const float* F = planes[a] + (size_t)b*NP;
        __syncthreads();
        for (int idx = t; idx < 18*258; idx += 256) {
            int rr = idx / 258, q = idx - rr*258;
            int gy = y0 - 1 + rr; gy = gy < 0 ? 0 : (gy > H-1 ? H-1 : gy);
            int gx = x0 - 1 + q;  gx = gx < 0 ? 0 : (gx > W-1 ? W-1 : gx);
            sh[rr][q] = F[gy*W + gx];
        }
        __syncthreads();
        float mean = fsum[a*8 + b] / 589824.f;
        #pragma unroll
        for (int r = 0; r < 16; r++) {
            float c = sh[r+1][t+1];
            float mx = c;
            mx = fmaxf(mx, sh[r  ][t]); mx = fmaxf(mx, sh[r  ][t+1]); mx = fmaxf(mx, sh[r  ][t+2]);
            mx = fmaxf(mx, sh[r+1][t]); mx = fmaxf(mx, sh[r+1][t+1]); mx = fmaxf(mx, sh[r+1][t+2]);
            mx = fmaxf(mx, sh[r+2][t]); mx = fmaxf(mx, sh[r+2][t+1]); mx = fmaxf(mx, sh[r+2][t+2]);
            if ((c == mx) && (c > mean)) condMask |= (1u << r);
        }
    }
    int wv = t >> 6, lane = t & 63;
    #pragma unroll
    for (int r = 0; r < 16; r++) {
        u64 m = __ballot((condMask >> r) & 1u);
        if (lane == 0)
            seedB[((size_t)b*H + y0 + r)*WPR + blockIdx.x*4 + wv] = m;
    }
}

// ---------------- Sobel grad mask (bitpacked) ----------------
__global__ void sobelK(const float* __restrict__ enh, u64* __restrict__ maskB) {
    int b = blockIdx.z, y = blockIdx.y, x = blockIdx.x*256 + threadIdx.x;
    const float* E = enh + (size_t)b*NP;
    int ym = y > 0 ? y-1 : 1, yp = y < H-1 ? y+1 : H-2;   // reflect101
    int xm = x > 0 ? x-1 : 1, xp = x < W-1 ? x+1 : W-2;
    float a00 = E[ym*W + xm], a01 = E[ym*W + x], a02 = E[ym*W + xp];
    float a10 = E[y*W + xm],                     a12 = E[y*W + xp];
    float a20 = E[yp*W + xm], a21 = E[yp*W + x], a22 = E[yp*W + xp];
    float gx = __fmaf_rn(-1.f, a00, 0.f);
    gx = __fmaf_rn( 1.f, a02, gx);
    gx = __fmaf_rn(-2.f, a10, gx);
    gx = __fmaf_rn( 2.f, a12, gx);
    gx = __fmaf_rn(-1.f, a20, gx);
    gx = __fmaf_rn( 1.f, a22, gx);
    float gy = __fmaf_rn(-1.f, a00, 0.f);
    gy = __fmaf_rn(-2.f, a01, gy);
    gy = __fmaf_rn(-1.f, a02, gy);
    gy = __fmaf_rn( 1.f, a20, gy);
    gy = __fmaf_rn( 2.f, a21, gy);
    gy = __fmaf_rn( 1.f, a22, gy);
    float s = __fadd_rn(__fmul_rn(gx, gx), __fmul_rn(gy, gy));
    float grad = (float)sqrt((double)s);
    const float THR = (float)(0.0789 + 1.0*0.0774);
    bool m = grad >= THR;
    u64 bits = __ballot(m);
    if ((threadIdx.x & 63) == 0) {
        int word = blockIdx.x*4 + (threadIdx.x >> 6);
        maskB[((size_t)b*H + y)*WPR + word] = bits;
    }
}

// ---------------- flood pass: 64-col x 768-row stripe in registers ----------------
__global__ __launch_bounds__(64) void floodColK(const u64* __restrict__ Mb,
                                                const u64* __restrict__ seedB,
                                                u64* __restrict__ Rb,
                                                unsigned* __restrict__ chg, int t) {
    if (t > 0 && chg[t-1] == 0) return;
    int b = blockIdx.y, wx = blockIdx.x, lane = threadIdx.x;
    const u64* M = Mb + (size_t)b*H*WPR;
    u64* R = Rb + (size_t)b*H*WPR;
    u64 m[12], r[12];
    #pragma unroll
    for (int j = 0; j < 12; j++) {
        int row = j*64 + lane;
        m[j] = M[row*WPR + wx];
        if (t == 0) r[j] = m[j] & seedB[((size_t)b*H + row)*WPR + wx];
        else        r[j] = R[row*WPR + wx];
    }
    unsigned cLmask = 0, cRmask = 0;
    {
        u64 CL[12], CR[12];
        #pragma unroll
        for (int j = 0; j < 12; j++) {
            int row = j*64 + lane;
            unsigned lv = 0, rv = 0;
            if (t > 0) {
                if (wx > 0)       lv = (unsigned)((R[row*WPR + wx - 1] >> 63) & 1ULL);
                if (wx < WPR - 1) rv = (unsigned)( R[row*WPR + wx + 1]        & 1ULL);
            }
            CL[j] = __ballot(lv != 0); CR[j] = __ballot(rv != 0);
        }
        #pragma unroll
        for (int j = 0; j < 12; j++) {
            u64 p = (j > 0)  ? CL[j-1] : 0ULL, n = (j < 11) ? CL[j+1] : 0ULL;
            u64 d = CL[j] | (CL[j] << 1) | (CL[j] >> 1) | (p >> 63) | (n << 63);
            cLmask |= (unsigned)((d >> lane) & 1ULL) << j;
            u64 p2 = (j > 0)  ? CR[j-1] : 0ULL, n2 = (j < 11) ? CR[j+1] : 0ULL;
            u64 d2 = CR[j] | (CR[j] << 1) | (CR[j] >> 1) | (p2 >> 63) | (n2 << 63);
            cRmask |= (unsigned)((d2 >> lane) & 1ULL) << j;
        }
    }
    bool grew = false;
    while (true) {
        bool any = false;
        #pragma unroll
        for (int j = 0; j < 12; j++) {
            u64 top = (j > 0)  ? __shfl(r[j-1], 63) : 0ULL;
            u64 bot = (j < 11) ? __shfl(r[j+1], 0)  : 0ULL;
            u64 up = __shfl_up(r[j], 1);   if (lane == 0)  up = top;
            u64 dn = __shfl_down(r[j], 1); if (lane == 63) dn = bot;
            u64 D = up | r[j] | dn;
            u64 nr = (D | (D << 1) | (D >> 1)
                      | (u64)((cLmask >> j) & 1u)
                      | ((u64)((cRmask >> j) & 1u) << 63)) & m[j];
            if (nr != r[j]) any = true;
            r[j] = nr;
        }
        if (!__any(any)) break;
        grew = true;
    }
    #pragma unroll
    for (int j = 0; j < 12; j++) R[(j*64 + lane)*WPR + wx] = r[j];
    if (__any(grew)) { if (lane == 0) atomicOr(&chg[t], 1u); }
}

// ---------------- final: out = (sigmoid?(pred)>0.5) | reach ----------------
__global__ void finalK(const float* __restrict__ pred, const u64* __restrict__ reachB,
                       const unsigned* __restrict__ sc, float* __restrict__ out) {
    int b = blockIdx.z, y = blockIdx.y, x = blockIdx.x*256 + threadIdx.x;
    float pmn = fdec(sc[16 + b]), pmx = fdec(sc[24 + b]);
    bool needSig = (pmx > 1.0f) || (pmn < 0.0f);
    float p = pred[((size_t)b*H + y)*W + x];
    float pv;
    if (needSig) {
        float e = (float)exp(-(double)p);
        pv = 1.f / (1.f + e);
    } else {
        pv = p;
    }
    bool on = pv > 0.5f;
    u64 w = reachB[((size_t)b*H + y)*WPR + (x >> 6)];
    on = on || ((w >> (x & 63)) & 1ULL);
    out[((size_t)b*H + y)*W + x] = on ? 1.f : 0.f;
}

extern "C" void kernel_launch(void* const* d_in, const int* in_sizes, int n_in,
                              void* d_out, int out_size, void* d_ws, size_t ws_size,
                              hipStream_t stream) {
    const float* pred = (const float*)d_in[0];
    const float* img  = (const float*)d_in[1];
    float* out = (float*)d_out;
    char* ws = (char*)d_ws;

    float*    wtab   = (float*)(ws + 1024);
    unsigned* sc     = (unsigned*)(ws + 16384);
    float*    fsum   = ((float*)sc) + 32;
    unsigned* chg    = sc + 64;
    float*    p12    = (float*)(ws + 20480);
    u64*      maskB  = (u64*)(ws + 1310720);
    u64*      seedB  = (u64*)(ws + 1900544);
    u64*      reachB = (u64*)(ws + 2490368);
    const size_t PL = (size_t)NB*NP;                      // floats per plane
    float* plane = (float*)(ws + 4194304);
    float* b0  = plane;          // gauss tmp
    float* b1  = plane + PL;     // enh
    float* h0c = plane + 2*PL; float* h0s = plane + 3*PL;
    float* h1c = plane + 4*PL;
    float* h2c = plane + 5*PL; float* h2s = plane + 6*PL;
    float* h3c = plane + 7*PL;
    float* f0  = plane + 8*PL; float* f1 = plane + 9*PL;
    float* f2  = plane + 10*PL; float* f3 = plane + 11*PL;

    const float* gpadH = wtab;
    const float* gpadV = wtab + 128;

    initK<<<1, 256, 0, stream>>>(wtab, sc);
    reduceK<<<dim3(64, 8), 256, 0, stream>>>(img, pred, sc);

    dim3 gRow(768, 8);            // one image row per block (H passes)
    dim3 g3(3, H, 8);             // per-pixel kernels

    gaussHK2<<<gRow, 192, 0, stream>>>(img, b0, gpadH, sc);
    gaussVK4<<<2304, 128, 0, stream>>>(b0, img, b1, gpadV, sc);

    sobelK<<<g3, 256, 0, stream>>>(b1, maskB);

    gaborHF<<<gRow, 192, 0, stream>>>(b1, h0c, h0s, h1c, h2c, h2s, h3c, wtab);

    // angles 0 (R12, cos+sin) + 1 (R17, cos)
    gaborV2<<<2304, 128, 0, stream>>>(h0c, h0s, h1c, f0, f1,
                                      wtab + 768, wtab + 896, wtab + 1024,
                                      p12, p12 + P12N);
    // angles 2 (R12, cos+sin) + 3 (R17, cos)
    gaborV2<<<2304, 128, 0, stream>>>(h2c, h2s, h3c, f2, f3,
                                      wtab + 1152, wtab + 1280, wtab + 1408,
                                      p12 + 2*P12N, p12 + 3*P12N);
    sumKAll<<<dim3(8, 4), 256, 0, stream>>>(p12, fsum);

    seedK4<<<dim3(3, 48, 8), 256, 0, stream>>>(f0, f1, f2, f3, fsum, seedB);

    for (int t = 0; t < FLOOD_PASSES; t++)
        floodColK<<<dim3(12, 8), 64, 0, stream>>>(maskB, seedB, reachB, chg, t);
    finalK<<<g3, 256, 0, stream>>>(pred, reachB, sc, out);
}